// Round 1
// baseline (14236.855 us; speedup 1.0000x reference)
//
#include <hip/hip_runtime.h>
#include <cstdint>
#include <cstddef>

#define D64 64
static constexpr int kNU   = 215904;   // N_USERS
static constexpr int kNS   = 275904;   // N_S
static constexpr int kNT   = 265904;   // N_T
static constexpr int kNSH  = 4096;     // N_SHARED
static constexpr int kNNZ  = 2000000;
static constexpr int kNSrcItems = 60000;
static constexpr int kNTgtItems = 50000;
static constexpr float kTinv = 0.2f;   // 1/T

// ---------------- SpMM: y[row] += val * x[col], atomic scatter ----------------
__global__ void spmm_kernel(const int* __restrict__ idx, const float* __restrict__ vals,
                            const float* __restrict__ x, float* __restrict__ y, int nnz) {
  int e = blockIdx.x * 16 + (threadIdx.x >> 4);
  if (e >= nnz) return;
  int r = idx[e];
  int c = idx[nnz + e];
  float v = vals[e];
  int q = (threadIdx.x & 15) << 2;
  const float4 xv = *reinterpret_cast<const float4*>(x + (size_t)c * D64 + q);
  float* yp = y + (size_t)r * D64 + q;
  atomicAdd(yp + 0, v * xv.x);
  atomicAdd(yp + 1, v * xv.y);
  atomicAdd(yp + 2, v * xv.z);
  atomicAdd(yp + 3, v * xv.w);
}

// ---------------- row-wise L2 normalize (optional) + strided store ----------------
template <int NORM>
__global__ void l2n_store(const float* __restrict__ in, float* __restrict__ out,
                          int nrows, size_t row0, int ostride, int coff) {
  int r = blockIdx.x * 4 + (threadIdx.x >> 6);
  if (r >= nrows) return;
  int d = threadIdx.x & 63;
  float v = in[(size_t)r * D64 + d];
  float wv = v;
  if (NORM) {
    float ss = v * v;
#pragma unroll
    for (int o = 32; o; o >>= 1) ss += __shfl_xor(ss, o);
    float n = fmaxf(sqrtf(ss), 1e-12f);
    wv = v / n;
  }
  out[(row0 + (size_t)r) * (size_t)ostride + coff + d] = wv;
}

// ---------------- s = exp((A @ B^T) / T), A,B: 4096x64 ----------------
__global__ void gemm_nt_exp(const float* __restrict__ A, const float* __restrict__ B,
                            float* __restrict__ S) {
  __shared__ float As[64][65];
  __shared__ float Bs[64][65];
  int i0 = blockIdx.y * 64, j0 = blockIdx.x * 64;
  int t = threadIdx.x;
  for (int l = t; l < 1024; l += 256) {
    int r = l >> 4, c = (l & 15) << 2;
    float4 a = *reinterpret_cast<const float4*>(A + (size_t)(i0 + r) * D64 + c);
    As[r][c] = a.x; As[r][c + 1] = a.y; As[r][c + 2] = a.z; As[r][c + 3] = a.w;
    float4 b = *reinterpret_cast<const float4*>(B + (size_t)(j0 + r) * D64 + c);
    Bs[r][c] = b.x; Bs[r][c + 1] = b.y; Bs[r][c + 2] = b.z; Bs[r][c + 3] = b.w;
  }
  __syncthreads();
  int j = t & 63, rgrp = t >> 6;
  float acc[16];
#pragma unroll
  for (int ii = 0; ii < 16; ++ii) acc[ii] = 0.f;
  for (int k = 0; k < 64; ++k) {
    float bv = Bs[j][k];
#pragma unroll
    for (int ii = 0; ii < 16; ++ii) acc[ii] += As[rgrp * 16 + ii][k] * bv;
  }
#pragma unroll
  for (int ii = 0; ii < 16; ++ii)
    S[(size_t)(i0 + rgrp * 16 + ii) * kNSH + j0 + j] = expf(acc[ii] * kTinv);
}

// ---------------- skinny GEMM: C[M x 64] = op(A) @ X, epilogues ----------------
// TRANS=0: C_rd = sum_k A[r][k] X[k][d];  TRANS=1: C_rd = sum_k A[k][r] X[k][d]
// EPI 0: C=acc; 1: C=ADD + acc/max(SC[r],1e-12); 2: C=relu((acc+ADD)/SC[r])
template <int TRANS, int EPI>
__global__ void sk_gemm(const float* __restrict__ A, int lda,
                        const float* __restrict__ X,
                        const float* __restrict__ ADD,
                        const float* __restrict__ SC,
                        float* __restrict__ C, int M, int K) {
  __shared__ float Xs[64][65];
  __shared__ float As[16][65];
  int r0 = blockIdx.x * 16;
  int t = threadIdx.x;
  int d = t & 63, rg = t >> 6;
  float acc[4] = {0.f, 0.f, 0.f, 0.f};
  for (int k0 = 0; k0 < K; k0 += 64) {
    for (int l = t; l < 1024; l += 256) {
      int r = l >> 4, c = (l & 15) << 2;
      float4 xv = *reinterpret_cast<const float4*>(X + (size_t)(k0 + r) * D64 + c);
      Xs[r][c] = xv.x; Xs[r][c + 1] = xv.y; Xs[r][c + 2] = xv.z; Xs[r][c + 3] = xv.w;
    }
    if (TRANS == 0) {
      int r = t >> 4, c = (t & 15) << 2;
      float4 av = *reinterpret_cast<const float4*>(A + (size_t)(r0 + r) * lda + k0 + c);
      As[r][c] = av.x; As[r][c + 1] = av.y; As[r][c + 2] = av.z; As[r][c + 3] = av.w;
    } else {
      int i = t >> 2, c = (t & 3) << 2;
      float4 av = *reinterpret_cast<const float4*>(A + (size_t)(k0 + i) * lda + r0 + c);
      As[c][i] = av.x; As[c + 1][i] = av.y; As[c + 2][i] = av.z; As[c + 3][i] = av.w;
    }
    __syncthreads();
    for (int k = 0; k < 64; ++k) {
      float xv = Xs[k][d];
#pragma unroll
      for (int rr = 0; rr < 4; ++rr) acc[rr] += As[rg * 4 + rr][k] * xv;
    }
    __syncthreads();
  }
#pragma unroll
  for (int rr = 0; rr < 4; ++rr) {
    int r = r0 + rg * 4 + rr;
    size_t off = (size_t)r * D64 + d;
    float v;
    if (EPI == 0) v = acc[rr];
    else if (EPI == 1) v = ADD[off] + acc[rr] / fmaxf(SC[r], 1e-12f);
    else v = fmaxf((acc[rr] + ADD[off]) / SC[r], 0.f);
    C[off] = v;
  }
}

// ---------------- row reduce: out[i] = sum_j S[i][j]*(w?w[j]:1) (+1) ----------------
template <int W, int P1>
__global__ void row_reduce(const float* __restrict__ S, const float* __restrict__ w,
                           float* __restrict__ out) {
  int i = blockIdx.x;
  const float* row = S + (size_t)i * kNSH;
  float acc = 0.f;
  for (int j = threadIdx.x; j < kNSH; j += 256) acc += W ? row[j] * w[j] : row[j];
#pragma unroll
  for (int o = 32; o; o >>= 1) acc += __shfl_xor(acc, o);
  __shared__ float red[4];
  if ((threadIdx.x & 63) == 0) red[threadIdx.x >> 6] = acc;
  __syncthreads();
  if (threadIdx.x == 0) {
    float r2 = red[0] + red[1] + red[2] + red[3];
    out[i] = P1 ? r2 + 1.f : r2;
  }
}

// ---------------- col reduce (atomic partials): out[j] += sum_i S[i][j]*(w?w[i]:1) ----------------
template <int W>
__global__ void col_reduce(const float* __restrict__ S, const float* __restrict__ w,
                           float* __restrict__ out) {
  int j = blockIdx.x * 64 + (threadIdx.x & 63);
  int i0 = blockIdx.y * 256 + (threadIdx.x >> 6) * 64;
  float acc = 0.f;
  for (int i = i0; i < i0 + 64; ++i) {
    float sv = S[(size_t)i * kNSH + j];
    acc += W ? sv * w[i] : sv;
  }
  __shared__ float part[4][64];
  part[threadIdx.x >> 6][threadIdx.x & 63] = acc;
  __syncthreads();
  if (threadIdx.x < 64) {
    float r2 = part[0][threadIdx.x] + part[1][threadIdx.x] + part[2][threadIdx.x] + part[3][threadIdx.x];
    atomicAdd(&out[j], r2);
  }
}

__global__ void add1_kernel(float* __restrict__ v) {
  int i = blockIdx.x * 256 + threadIdx.x;
  if (i < kNSH) v[i] += 1.f;
}

__global__ void avg_update(float* __restrict__ emb, const float* __restrict__ it) {
  int i = blockIdx.x * 256 + threadIdx.x;
  emb[i] = 0.5f * (emb[i] + it[i]);
}

extern "C" void kernel_launch(void* const* d_in, const int* in_sizes, int n_in,
                              void* d_out, int out_size, void* d_ws, size_t ws_size,
                              hipStream_t stream) {
  const float* src_user = (const float*)d_in[0];
  const float* tgt_user = (const float*)d_in[1];
  const float* src_item = (const float*)d_in[2];
  const float* tgt_item = (const float*)d_in[3];
  const float* mapping  = (const float*)d_in[4];
  const float* s_vals   = (const float*)d_in[5];
  const float* t_vals   = (const float*)d_in[6];
  const int*   s_idx    = (const int*)d_in[7];
  const int*   t_idx    = (const int*)d_in[8];
  float* out = (float*)d_out;

  float* w = (float*)d_ws;
  size_t o = 0;
  float* es[2]; float* et[2];
  es[0] = w + o; o += (size_t)kNS * D64;
  es[1] = w + o; o += (size_t)kNS * D64;
  et[0] = w + o; o += (size_t)kNT * D64;
  et[1] = w + o; o += (size_t)kNT * D64;
  float* S    = w + o; o += (size_t)kNSH * kNSH;
  float* tmp  = w + o; o += (size_t)kNSH * D64;
  float* src2 = w + o; o += (size_t)kNSH * D64;
  float* tgt2 = w + o; o += (size_t)kNSH * D64;
  float* itS  = w + o; o += (size_t)kNSH * D64;
  float* itT  = w + o; o += (size_t)kNSH * D64;
  float* ybuf = w + o; o += (size_t)kNSH * D64;
  float* rs = w + o; o += kNSH;
  float* cs = w + o; o += kNSH;
  float* Ds = w + o; o += kNSH;
  float* Dt = w + o; o += kNSH;

  // ---- concat inputs into es[0], et[0] ----
  hipMemcpyAsync(es[0], src_user, (size_t)kNU * D64 * 4, hipMemcpyDeviceToDevice, stream);
  hipMemcpyAsync(es[0] + (size_t)kNU * D64, src_item, (size_t)kNSrcItems * D64 * 4, hipMemcpyDeviceToDevice, stream);
  hipMemcpyAsync(et[0], tgt_user, (size_t)kNU * D64 * 4, hipMemcpyDeviceToDevice, stream);
  hipMemcpyAsync(et[0] + (size_t)kNU * D64, tgt_item, (size_t)kNTgtItems * D64 * 4, hipMemcpyDeviceToDevice, stream);

  // ---- output column block 0: raw concat ----
  l2n_store<0><<<(kNS + 3) / 4, 256, 0, stream>>>(es[0], out, kNS, 0, 256, 0);
  l2n_store<0><<<(kNT + 3) / 4, 256, 0, stream>>>(et[0], out, kNT, (size_t)kNS, 256, 0);

  int cur = 0;
  const int spmm_grid = (kNNZ + 15) / 16;
  for (int k = 0; k < 3; ++k) {
    int nxt = cur ^ 1;
    hipMemsetAsync(es[nxt], 0, (size_t)kNS * D64 * 4, stream);
    hipMemsetAsync(et[nxt], 0, (size_t)kNT * D64 * 4, stream);
    spmm_kernel<<<spmm_grid, 256, 0, stream>>>(s_idx, s_vals, es[cur], es[nxt], kNNZ);
    spmm_kernel<<<spmm_grid, 256, 0, stream>>>(t_idx, t_vals, et[cur], et[nxt], kNNZ);

    if (k == 0) {
      float* src0 = es[nxt];   // first 4096 rows = shared users
      float* tgt0 = et[nxt];
      // tmp = src0 @ mapping
      sk_gemm<0, 0><<<256, 256, 0, stream>>>(src0, D64, mapping, nullptr, nullptr, tmp, kNSH, 64);
      // S = exp(tmp @ tgt0^T / T)
      gemm_nt_exp<<<dim3(64, 64), 256, 0, stream>>>(tmp, tgt0, S);
      // rs, cs
      row_reduce<0, 0><<<kNSH, 256, 0, stream>>>(S, nullptr, rs);
      hipMemsetAsync(cs, 0, kNSH * 4, stream);
      col_reduce<0><<<dim3(64, 16), 256, 0, stream>>>(S, nullptr, cs);
      // src2 = src0 + (S @ tgt0) / rs ; tgt2 = tgt0 + (S^T @ src2) / cs
      sk_gemm<0, 1><<<256, 256, 0, stream>>>(S, kNSH, tgt0, src0, rs, src2, kNSH, kNSH);
      sk_gemm<1, 1><<<256, 256, 0, stream>>>(S, kNSH, src2, tgt0, cs, tgt2, kNSH, kNSH);
      // Ds = S@cs + 1 ; Dt = S^T@rs + 1
      row_reduce<1, 1><<<kNSH, 256, 0, stream>>>(S, cs, Ds);
      hipMemsetAsync(Dt, 0, kNSH * 4, stream);
      col_reduce<1><<<dim3(64, 16), 256, 0, stream>>>(S, rs, Dt);
      add1_kernel<<<16, 256, 0, stream>>>(Dt);
      // 3 propagation iterations (factored: (S S^T + I)x = S(S^T x) + x)
      float* pa = src2; float* pb = itS;
      float* qa = tgt2; float* qb = itT;
      for (int itn = 0; itn < 3; ++itn) {
        sk_gemm<1, 0><<<256, 256, 0, stream>>>(S, kNSH, pa, nullptr, nullptr, ybuf, kNSH, kNSH);
        sk_gemm<0, 2><<<256, 256, 0, stream>>>(S, kNSH, ybuf, pa, Ds, pb, kNSH, kNSH);
        l2n_store<1><<<kNSH / 4, 256, 0, stream>>>(pb, pb, kNSH, 0, D64, 0);
        sk_gemm<0, 0><<<256, 256, 0, stream>>>(S, kNSH, qa, nullptr, nullptr, ybuf, kNSH, kNSH);
        sk_gemm<1, 2><<<256, 256, 0, stream>>>(S, kNSH, ybuf, qa, Dt, qb, kNSH, kNSH);
        l2n_store<1><<<kNSH / 4, 256, 0, stream>>>(qb, qb, kNSH, 0, D64, 0);
        float* t0 = pa; pa = pb; pb = t0;
        float* t1 = qa; qa = qb; qb = t1;
      }
      // final: emb[:4096] = 0.5*(raw + iterated)
      avg_update<<<(kNSH * D64) / 256, 256, 0, stream>>>(src0, pa);
      avg_update<<<(kNSH * D64) / 256, 256, 0, stream>>>(tgt0, qa);
    }

    // output column block k+1 : l2n
    l2n_store<1><<<(kNS + 3) / 4, 256, 0, stream>>>(es[nxt], out, kNS, 0, 256, 64 * (k + 1));
    l2n_store<1><<<(kNT + 3) / 4, 256, 0, stream>>>(et[nxt], out, kNT, (size_t)kNS, 256, 64 * (k + 1));

    cur = nxt;
  }
}

// Round 2
// 5082.059 us; speedup vs baseline: 2.8014x; 2.8014x over previous
//
#include <hip/hip_runtime.h>
#include <cstdint>
#include <cstddef>

#define D64 64
static constexpr int kNU   = 215904;   // N_USERS
static constexpr int kNS   = 275904;   // N_S
static constexpr int kNT   = 265904;   // N_T
static constexpr int kNSH  = 4096;     // N_SHARED
static constexpr int kNNZ  = 2000000;
static constexpr int kNSrcItems = 60000;
static constexpr int kNTgtItems = 50000;
static constexpr float kTinv = 0.2f;   // 1/T
static constexpr int kScanCh = 2048;   // elements per scan block

// ================= CSR build =================
__global__ void histo_kernel(const int* __restrict__ idx, int* __restrict__ cnt, int nnz) {
  int e = blockIdx.x * 256 + threadIdx.x;
  if (e < nnz) atomicAdd(&cnt[idx[e]], 1);
}

// exclusive scan, pass 1: per-block scan (no global offset), block sums out
__global__ void scan_pass1(const int* __restrict__ in, int* __restrict__ out,
                           int* __restrict__ blksum, int n) {
  __shared__ int ts[256];
  int base = blockIdx.x * kScanCh;
  int t = threadIdx.x;
  int local[8];
  int s = 0;
#pragma unroll
  for (int i = 0; i < 8; ++i) {
    int g = base + t * 8 + i;
    int v = (g < n) ? in[g] : 0;
    local[i] = s;
    s += v;
  }
  ts[t] = s;
  __syncthreads();
  for (int off = 1; off < 256; off <<= 1) {
    int v = (t >= off) ? ts[t - off] : 0;
    __syncthreads();
    ts[t] += v;
    __syncthreads();
  }
  int excl = (t == 0) ? 0 : ts[t - 1];
  if (t == 255) blksum[blockIdx.x] = ts[255];
#pragma unroll
  for (int i = 0; i < 8; ++i) {
    int g = base + t * 8 + i;
    if (g < n) out[g] = excl + local[i];
  }
}

// pass 2: serial scan of block sums (nb <= ~140)
__global__ void scan_pass2(int* __restrict__ blksum, int nb) {
  if (threadIdx.x == 0 && blockIdx.x == 0) {
    int s = 0;
    for (int i = 0; i < nb; ++i) { int v = blksum[i]; blksum[i] = s; s += v; }
  }
}

// pass 3: add block offsets; also initialize cursor = row_ptr
__global__ void scan_pass3(int* __restrict__ out, int* __restrict__ cursor,
                           const int* __restrict__ blksum, int n) {
  int base = blockIdx.x * kScanCh;
  int add = blksum[blockIdx.x];
  int t = threadIdx.x;
#pragma unroll
  for (int i = 0; i < 8; ++i) {
    int g = base + t * 8 + i;
    if (g < n) { int v = out[g] + add; out[g] = v; cursor[g] = v; }
  }
}

__global__ void csr_scatter(const int* __restrict__ idx, const float* __restrict__ vals,
                            int* __restrict__ cursor, int* __restrict__ cols,
                            float* __restrict__ vout, int nnz) {
  int e = blockIdx.x * 256 + threadIdx.x;
  if (e >= nnz) return;
  int r = idx[e];
  int p = atomicAdd(&cursor[r], 1);
  cols[p] = idx[nnz + e];
  vout[p] = vals[e];
}

// ================= gather SpMM (CSR): y[r] = sum val*x[col] =================
__global__ void spmm_csr(const int* __restrict__ row_ptr, const int* __restrict__ row_end,
                         const int* __restrict__ cols, const float* __restrict__ vals,
                         const float* __restrict__ x, float* __restrict__ y, int n) {
  int r = blockIdx.x * 16 + (threadIdx.x >> 4);
  if (r >= n) return;
  int q = (threadIdx.x & 15) << 2;
  int beg = row_ptr[r], end = row_end[r];
  float4 acc = {0.f, 0.f, 0.f, 0.f};
  for (int i = beg; i < end; ++i) {
    int c = cols[i];
    float v = vals[i];
    const float4 xv = *reinterpret_cast<const float4*>(x + (size_t)c * D64 + q);
    acc.x = fmaf(v, xv.x, acc.x);
    acc.y = fmaf(v, xv.y, acc.y);
    acc.z = fmaf(v, xv.z, acc.z);
    acc.w = fmaf(v, xv.w, acc.w);
  }
  *reinterpret_cast<float4*>(y + (size_t)r * D64 + q) = acc;
}

// ---------------- row-wise L2 normalize (optional) + strided store ----------------
template <int NORM>
__global__ void l2n_store(const float* __restrict__ in, float* __restrict__ out,
                          int nrows, size_t row0, int ostride, int coff) {
  int r = blockIdx.x * 4 + (threadIdx.x >> 6);
  if (r >= nrows) return;
  int d = threadIdx.x & 63;
  float v = in[(size_t)r * D64 + d];
  float wv = v;
  if (NORM) {
    float ss = v * v;
#pragma unroll
    for (int o = 32; o; o >>= 1) ss += __shfl_xor(ss, o);
    float n = fmaxf(sqrtf(ss), 1e-12f);
    wv = v / n;
  }
  out[(row0 + (size_t)r) * (size_t)ostride + coff + d] = wv;
}

// ---------------- s = exp((A @ B^T) / T), A,B: 4096x64 ----------------
__global__ void gemm_nt_exp(const float* __restrict__ A, const float* __restrict__ B,
                            float* __restrict__ S) {
  __shared__ float As[64][65];
  __shared__ float Bs[64][65];
  int i0 = blockIdx.y * 64, j0 = blockIdx.x * 64;
  int t = threadIdx.x;
  for (int l = t; l < 1024; l += 256) {
    int r = l >> 4, c = (l & 15) << 2;
    float4 a = *reinterpret_cast<const float4*>(A + (size_t)(i0 + r) * D64 + c);
    As[r][c] = a.x; As[r][c + 1] = a.y; As[r][c + 2] = a.z; As[r][c + 3] = a.w;
    float4 b = *reinterpret_cast<const float4*>(B + (size_t)(j0 + r) * D64 + c);
    Bs[r][c] = b.x; Bs[r][c + 1] = b.y; Bs[r][c + 2] = b.z; Bs[r][c + 3] = b.w;
  }
  __syncthreads();
  int j = t & 63, rgrp = t >> 6;
  float acc[16];
#pragma unroll
  for (int ii = 0; ii < 16; ++ii) acc[ii] = 0.f;
  for (int k = 0; k < 64; ++k) {
    float bv = Bs[j][k];
#pragma unroll
    for (int ii = 0; ii < 16; ++ii) acc[ii] += As[rgrp * 16 + ii][k] * bv;
  }
#pragma unroll
  for (int ii = 0; ii < 16; ++ii)
    S[(size_t)(i0 + rgrp * 16 + ii) * kNSH + j0 + j] = expf(acc[ii] * kTinv);
}

// ---------------- skinny GEMM: C[M x 64] = op(A) @ X, epilogues ----------------
template <int TRANS, int EPI>
__global__ void sk_gemm(const float* __restrict__ A, int lda,
                        const float* __restrict__ X,
                        const float* __restrict__ ADD,
                        const float* __restrict__ SC,
                        float* __restrict__ C, int M, int K) {
  __shared__ float Xs[64][65];
  __shared__ float As[16][65];
  int r0 = blockIdx.x * 16;
  int t = threadIdx.x;
  int d = t & 63, rg = t >> 6;
  float acc[4] = {0.f, 0.f, 0.f, 0.f};
  for (int k0 = 0; k0 < K; k0 += 64) {
    for (int l = t; l < 1024; l += 256) {
      int r = l >> 4, c = (l & 15) << 2;
      float4 xv = *reinterpret_cast<const float4*>(X + (size_t)(k0 + r) * D64 + c);
      Xs[r][c] = xv.x; Xs[r][c + 1] = xv.y; Xs[r][c + 2] = xv.z; Xs[r][c + 3] = xv.w;
    }
    if (TRANS == 0) {
      int r = t >> 4, c = (t & 15) << 2;
      float4 av = *reinterpret_cast<const float4*>(A + (size_t)(r0 + r) * lda + k0 + c);
      As[r][c] = av.x; As[r][c + 1] = av.y; As[r][c + 2] = av.z; As[r][c + 3] = av.w;
    } else {
      int i = t >> 2, c = (t & 3) << 2;
      float4 av = *reinterpret_cast<const float4*>(A + (size_t)(k0 + i) * lda + r0 + c);
      As[c][i] = av.x; As[c + 1][i] = av.y; As[c + 2][i] = av.z; As[c + 3][i] = av.w;
    }
    __syncthreads();
    for (int k = 0; k < 64; ++k) {
      float xv = Xs[k][d];
#pragma unroll
      for (int rr = 0; rr < 4; ++rr) acc[rr] += As[rg * 4 + rr][k] * xv;
    }
    __syncthreads();
  }
#pragma unroll
  for (int rr = 0; rr < 4; ++rr) {
    int r = r0 + rg * 4 + rr;
    size_t off = (size_t)r * D64 + d;
    float v;
    if (EPI == 0) v = acc[rr];
    else if (EPI == 1) v = ADD[off] + acc[rr] / fmaxf(SC[r], 1e-12f);
    else v = fmaxf((acc[rr] + ADD[off]) / SC[r], 0.f);
    C[off] = v;
  }
}

// ---------------- row reduce: out[i] = sum_j S[i][j]*(w?w[j]:1) (+1) ----------------
template <int W, int P1>
__global__ void row_reduce(const float* __restrict__ S, const float* __restrict__ w,
                           float* __restrict__ out) {
  int i = blockIdx.x;
  const float* row = S + (size_t)i * kNSH;
  float acc = 0.f;
  for (int j = threadIdx.x; j < kNSH; j += 256) acc += W ? row[j] * w[j] : row[j];
#pragma unroll
  for (int o = 32; o; o >>= 1) acc += __shfl_xor(acc, o);
  __shared__ float red[4];
  if ((threadIdx.x & 63) == 0) red[threadIdx.x >> 6] = acc;
  __syncthreads();
  if (threadIdx.x == 0) {
    float r2 = red[0] + red[1] + red[2] + red[3];
    out[i] = P1 ? r2 + 1.f : r2;
  }
}

// ---------------- col reduce (atomic partials): out[j] += sum_i S[i][j]*(w?w[i]:1) ----------------
template <int W>
__global__ void col_reduce(const float* __restrict__ S, const float* __restrict__ w,
                           float* __restrict__ out) {
  int j = blockIdx.x * 64 + (threadIdx.x & 63);
  int i0 = blockIdx.y * 256 + (threadIdx.x >> 6) * 64;
  float acc = 0.f;
  for (int i = i0; i < i0 + 64; ++i) {
    float sv = S[(size_t)i * kNSH + j];
    acc += W ? sv * w[i] : sv;
  }
  __shared__ float part[4][64];
  part[threadIdx.x >> 6][threadIdx.x & 63] = acc;
  __syncthreads();
  if (threadIdx.x < 64) {
    float r2 = part[0][threadIdx.x] + part[1][threadIdx.x] + part[2][threadIdx.x] + part[3][threadIdx.x];
    atomicAdd(&out[j], r2);
  }
}

__global__ void add1_kernel(float* __restrict__ v) {
  int i = blockIdx.x * 256 + threadIdx.x;
  if (i < kNSH) v[i] += 1.f;
}

__global__ void avg_update(float* __restrict__ emb, const float* __restrict__ it) {
  int i = blockIdx.x * 256 + threadIdx.x;
  emb[i] = 0.5f * (emb[i] + it[i]);
}

extern "C" void kernel_launch(void* const* d_in, const int* in_sizes, int n_in,
                              void* d_out, int out_size, void* d_ws, size_t ws_size,
                              hipStream_t stream) {
  const float* src_user = (const float*)d_in[0];
  const float* tgt_user = (const float*)d_in[1];
  const float* src_item = (const float*)d_in[2];
  const float* tgt_item = (const float*)d_in[3];
  const float* mapping  = (const float*)d_in[4];
  const float* s_vals   = (const float*)d_in[5];
  const float* t_vals   = (const float*)d_in[6];
  const int*   s_idx    = (const int*)d_in[7];
  const int*   t_idx    = (const int*)d_in[8];
  float* out = (float*)d_out;

  float* w = (float*)d_ws;
  size_t o = 0;
  float* es[2]; float* et[2];
  es[0] = w + o; o += (size_t)kNS * D64;
  es[1] = w + o; o += (size_t)kNS * D64;
  et[0] = w + o; o += (size_t)kNT * D64;
  et[1] = w + o; o += (size_t)kNT * D64;
  float* S    = w + o; o += (size_t)kNSH * kNSH;
  float* tmp  = w + o; o += (size_t)kNSH * D64;
  float* src2 = w + o; o += (size_t)kNSH * D64;
  float* tgt2 = w + o; o += (size_t)kNSH * D64;
  float* itS  = w + o; o += (size_t)kNSH * D64;
  float* itT  = w + o; o += (size_t)kNSH * D64;
  float* ybuf = w + o; o += (size_t)kNSH * D64;
  float* rs = w + o; o += kNSH;
  float* cs = w + o; o += kNSH;
  float* Ds = w + o; o += kNSH;
  float* Dt = w + o; o += kNSH;
  // CSR workspace
  int* iw = (int*)(w + o);
  size_t io = 0;
  int* sPtr = iw + io; io += kNS;
  int* sEnd = iw + io; io += kNS;   // cursor during scatter; row ends after
  int* sCnt = iw + io; io += kNS;
  int* sCol = iw + io; io += kNNZ;
  int* tPtr = iw + io; io += kNT;
  int* tEnd = iw + io; io += kNT;
  int* tCnt = iw + io; io += kNT;
  int* tCol = iw + io; io += kNNZ;
  int* blk  = iw + io; io += 512;
  float* sVal = (float*)(iw + io); io += kNNZ;
  float* tVal = (float*)(iw + io); io += kNNZ;

  const int nbS = (kNS + kScanCh - 1) / kScanCh;
  const int nbT = (kNT + kScanCh - 1) / kScanCh;
  const int egrid = (kNNZ + 255) / 256;

  // ---- build CSR for both graphs ----
  hipMemsetAsync(sCnt, 0, (size_t)kNS * 4, stream);
  hipMemsetAsync(tCnt, 0, (size_t)kNT * 4, stream);
  histo_kernel<<<egrid, 256, 0, stream>>>(s_idx, sCnt, kNNZ);
  histo_kernel<<<egrid, 256, 0, stream>>>(t_idx, tCnt, kNNZ);
  scan_pass1<<<nbS, 256, 0, stream>>>(sCnt, sPtr, blk, kNS);
  scan_pass2<<<1, 64, 0, stream>>>(blk, nbS);
  scan_pass3<<<nbS, 256, 0, stream>>>(sPtr, sEnd, blk, kNS);
  scan_pass1<<<nbT, 256, 0, stream>>>(tCnt, tPtr, blk, kNT);
  scan_pass2<<<1, 64, 0, stream>>>(blk, nbT);
  scan_pass3<<<nbT, 256, 0, stream>>>(tPtr, tEnd, blk, kNT);
  csr_scatter<<<egrid, 256, 0, stream>>>(s_idx, s_vals, sEnd, sCol, sVal, kNNZ);
  csr_scatter<<<egrid, 256, 0, stream>>>(t_idx, t_vals, tEnd, tCol, tVal, kNNZ);
  // after scatter: sEnd[r] == row end offset

  // ---- concat inputs into es[0], et[0] ----
  hipMemcpyAsync(es[0], src_user, (size_t)kNU * D64 * 4, hipMemcpyDeviceToDevice, stream);
  hipMemcpyAsync(es[0] + (size_t)kNU * D64, src_item, (size_t)kNSrcItems * D64 * 4, hipMemcpyDeviceToDevice, stream);
  hipMemcpyAsync(et[0], tgt_user, (size_t)kNU * D64 * 4, hipMemcpyDeviceToDevice, stream);
  hipMemcpyAsync(et[0] + (size_t)kNU * D64, tgt_item, (size_t)kNTgtItems * D64 * 4, hipMemcpyDeviceToDevice, stream);

  // ---- output column block 0: raw concat ----
  l2n_store<0><<<(kNS + 3) / 4, 256, 0, stream>>>(es[0], out, kNS, 0, 256, 0);
  l2n_store<0><<<(kNT + 3) / 4, 256, 0, stream>>>(et[0], out, kNT, (size_t)kNS, 256, 0);

  int cur = 0;
  for (int k = 0; k < 3; ++k) {
    int nxt = cur ^ 1;
    spmm_csr<<<(kNS + 15) / 16, 256, 0, stream>>>(sPtr, sEnd, sCol, sVal, es[cur], es[nxt], kNS);
    spmm_csr<<<(kNT + 15) / 16, 256, 0, stream>>>(tPtr, tEnd, tCol, tVal, et[cur], et[nxt], kNT);

    if (k == 0) {
      float* src0 = es[nxt];   // first 4096 rows = shared users
      float* tgt0 = et[nxt];
      // tmp = src0 @ mapping
      sk_gemm<0, 0><<<256, 256, 0, stream>>>(src0, D64, mapping, nullptr, nullptr, tmp, kNSH, 64);
      // S = exp(tmp @ tgt0^T / T)
      gemm_nt_exp<<<dim3(64, 64), 256, 0, stream>>>(tmp, tgt0, S);
      // rs, cs
      row_reduce<0, 0><<<kNSH, 256, 0, stream>>>(S, nullptr, rs);
      hipMemsetAsync(cs, 0, kNSH * 4, stream);
      col_reduce<0><<<dim3(64, 16), 256, 0, stream>>>(S, nullptr, cs);
      // src2 = src0 + (S @ tgt0) / rs ; tgt2 = tgt0 + (S^T @ src2) / cs
      sk_gemm<0, 1><<<256, 256, 0, stream>>>(S, kNSH, tgt0, src0, rs, src2, kNSH, kNSH);
      sk_gemm<1, 1><<<256, 256, 0, stream>>>(S, kNSH, src2, tgt0, cs, tgt2, kNSH, kNSH);
      // Ds = S@cs + 1 ; Dt = S^T@rs + 1
      row_reduce<1, 1><<<kNSH, 256, 0, stream>>>(S, cs, Ds);
      hipMemsetAsync(Dt, 0, kNSH * 4, stream);
      col_reduce<1><<<dim3(64, 16), 256, 0, stream>>>(S, rs, Dt);
      add1_kernel<<<16, 256, 0, stream>>>(Dt);
      // 3 propagation iterations (factored: (S S^T + I)x = S(S^T x) + x)
      float* pa = src2; float* pb = itS;
      float* qa = tgt2; float* qb = itT;
      for (int itn = 0; itn < 3; ++itn) {
        sk_gemm<1, 0><<<256, 256, 0, stream>>>(S, kNSH, pa, nullptr, nullptr, ybuf, kNSH, kNSH);
        sk_gemm<0, 2><<<256, 256, 0, stream>>>(S, kNSH, ybuf, pa, Ds, pb, kNSH, kNSH);
        l2n_store<1><<<kNSH / 4, 256, 0, stream>>>(pb, pb, kNSH, 0, D64, 0);
        sk_gemm<0, 0><<<256, 256, 0, stream>>>(S, kNSH, qa, nullptr, nullptr, ybuf, kNSH, kNSH);
        sk_gemm<1, 2><<<256, 256, 0, stream>>>(S, kNSH, ybuf, qa, Dt, qb, kNSH, kNSH);
        l2n_store<1><<<kNSH / 4, 256, 0, stream>>>(qb, qb, kNSH, 0, D64, 0);
        float* t0 = pa; pa = pb; pb = t0;
        float* t1 = qa; qa = qb; qb = t1;
      }
      // final: emb[:4096] = 0.5*(raw + iterated)
      avg_update<<<(kNSH * D64) / 256, 256, 0, stream>>>(src0, pa);
      avg_update<<<(kNSH * D64) / 256, 256, 0, stream>>>(tgt0, qa);
    }

    // output column block k+1 : l2n
    l2n_store<1><<<(kNS + 3) / 4, 256, 0, stream>>>(es[nxt], out, kNS, 0, 256, 64 * (k + 1));
    l2n_store<1><<<(kNT + 3) / 4, 256, 0, stream>>>(et[nxt], out, kNT, (size_t)kNS, 256, 64 * (k + 1));

    cur = nxt;
  }
}

// Round 3
// 2770.573 us; speedup vs baseline: 5.1386x; 1.8343x over previous
//
#include <hip/hip_runtime.h>
#include <cstdint>
#include <cstddef>

#define D64 64
static constexpr int kNU   = 215904;   // N_USERS
static constexpr int kNS   = 275904;   // N_S
static constexpr int kNT   = 265904;   // N_T
static constexpr int kNSH  = 4096;     // N_SHARED
static constexpr int kNNZ  = 2000000;
static constexpr float kTinv = 0.2f;   // 1/T
static constexpr int kScanCh = 2048;

// ================= CSR build =================
__global__ void histo_kernel(const int* __restrict__ idx, int* __restrict__ cnt, int nnz) {
  int e = blockIdx.x * 256 + threadIdx.x;
  if (e < nnz) atomicAdd(&cnt[idx[e]], 1);
}

__global__ void scan_pass1(const int* __restrict__ in, int* __restrict__ out,
                           int* __restrict__ blksum, int n) {
  __shared__ int ts[256];
  int base = blockIdx.x * kScanCh;
  int t = threadIdx.x;
  int local[8];
  int s = 0;
#pragma unroll
  for (int i = 0; i < 8; ++i) {
    int g = base + t * 8 + i;
    int v = (g < n) ? in[g] : 0;
    local[i] = s;
    s += v;
  }
  ts[t] = s;
  __syncthreads();
  for (int off = 1; off < 256; off <<= 1) {
    int v = (t >= off) ? ts[t - off] : 0;
    __syncthreads();
    ts[t] += v;
    __syncthreads();
  }
  int excl = (t == 0) ? 0 : ts[t - 1];
  if (t == 255) blksum[blockIdx.x] = ts[255];
#pragma unroll
  for (int i = 0; i < 8; ++i) {
    int g = base + t * 8 + i;
    if (g < n) out[g] = excl + local[i];
  }
}

__global__ void scan_pass2(int* __restrict__ blksum, int nb) {
  if (threadIdx.x == 0 && blockIdx.x == 0) {
    int s = 0;
    for (int i = 0; i < nb; ++i) { int v = blksum[i]; blksum[i] = s; s += v; }
  }
}

__global__ void scan_pass3(int* __restrict__ out, int* __restrict__ cursor,
                           const int* __restrict__ blksum, int n) {
  int base = blockIdx.x * kScanCh;
  int add = blksum[blockIdx.x];
  int t = threadIdx.x;
#pragma unroll
  for (int i = 0; i < 8; ++i) {
    int g = base + t * 8 + i;
    if (g < n) { int v = out[g] + add; out[g] = v; cursor[g] = v; }
  }
}

__global__ void csr_scatter(const int* __restrict__ idx, const float* __restrict__ vals,
                            int* __restrict__ cursor, int* __restrict__ cols,
                            float* __restrict__ vout, int nnz) {
  int e = blockIdx.x * 256 + threadIdx.x;
  if (e >= nnz) return;
  int r = idx[e];
  int p = atomicAdd(&cursor[r], 1);
  cols[p] = idx[nnz + e];
  vout[p] = vals[e];
}

// ================= gather SpMM (CSR), split source =================
__global__ void spmm_csr2(const int* __restrict__ row_ptr, const int* __restrict__ row_end,
                          const int* __restrict__ cols, const float* __restrict__ vals,
                          const float* __restrict__ x0, const float* __restrict__ x1, int n0,
                          float* __restrict__ y, int n) {
  int r = blockIdx.x * 16 + (threadIdx.x >> 4);
  if (r >= n) return;
  int q = (threadIdx.x & 15) << 2;
  int beg = row_ptr[r], end = row_end[r];
  float4 acc = {0.f, 0.f, 0.f, 0.f};
  for (int i = beg; i < end; ++i) {
    int c = cols[i];
    float v = vals[i];
    const float* xp = (c < n0) ? (x0 + ((size_t)c << 6)) : (x1 + ((size_t)(c - n0) << 6));
    const float4 xv = *reinterpret_cast<const float4*>(xp + q);
    acc.x = fmaf(v, xv.x, acc.x);
    acc.y = fmaf(v, xv.y, acc.y);
    acc.z = fmaf(v, xv.z, acc.z);
    acc.w = fmaf(v, xv.w, acc.w);
  }
  *reinterpret_cast<float4*>(y + (size_t)r * D64 + q) = acc;
}

// ---------------- raw concat -> out col-block 0 ----------------
__global__ void raw_store(const float* __restrict__ a, const float* __restrict__ b, int n0,
                          float* __restrict__ out, int nrows, size_t row0) {
  int r = blockIdx.x * 4 + (threadIdx.x >> 6);
  if (r >= nrows) return;
  int d = threadIdx.x & 63;
  float v = (r < n0) ? a[(size_t)r * D64 + d] : b[(size_t)(r - n0) * D64 + d];
  out[(row0 + (size_t)r) * 256 + d] = v;
}

// ---------------- row-wise L2 normalize + strided store ----------------
__global__ void l2n_store(const float* __restrict__ in, float* __restrict__ out,
                          int nrows, size_t row0, int coff) {
  int r = blockIdx.x * 4 + (threadIdx.x >> 6);
  if (r >= nrows) return;
  int d = threadIdx.x & 63;
  float v = in[(size_t)r * D64 + d];
  float ss = v * v;
#pragma unroll
  for (int o = 32; o; o >>= 1) ss += __shfl_xor(ss, o);
  float n = fmaxf(sqrtf(ss), 1e-12f);
  out[(row0 + (size_t)r) * 256 + coff + d] = v / n;
}

// ---------------- small GEMM for tmp = src0 @ mapping (K=64) ----------------
__global__ void map_gemm(const float* __restrict__ A, const float* __restrict__ X,
                         float* __restrict__ C) {
  __shared__ float Xs[64][65];
  __shared__ float As[16][65];
  int r0 = blockIdx.x * 16;
  int t = threadIdx.x;
  int d = t & 63, rg = t >> 6;
  float acc[4] = {0.f, 0.f, 0.f, 0.f};
  {
    for (int l = t; l < 1024; l += 256) {
      int r = l >> 4, c = (l & 15) << 2;
      float4 xv = *reinterpret_cast<const float4*>(X + (size_t)r * D64 + c);
      Xs[r][c] = xv.x; Xs[r][c + 1] = xv.y; Xs[r][c + 2] = xv.z; Xs[r][c + 3] = xv.w;
    }
    int r = t >> 4, c = (t & 15) << 2;
    float4 av = *reinterpret_cast<const float4*>(A + (size_t)(r0 + r) * D64 + c);
    As[r][c] = av.x; As[r][c + 1] = av.y; As[r][c + 2] = av.z; As[r][c + 3] = av.w;
    __syncthreads();
    for (int k = 0; k < 64; ++k) {
      float xv = Xs[k][d];
#pragma unroll
      for (int rr = 0; rr < 4; ++rr) acc[rr] += As[rg * 4 + rr][k] * xv;
    }
  }
#pragma unroll
  for (int rr = 0; rr < 4; ++rr)
    C[(size_t)(r0 + rg * 4 + rr) * D64 + d] = acc[rr];
}

// ---------------- S = exp((A @ B^T)/T) + fused row/col sums ----------------
__global__ void gemm_exp_rc(const float* __restrict__ A, const float* __restrict__ B,
                            float* __restrict__ S, float* __restrict__ rs, float* __restrict__ cs) {
  __shared__ float As[64][65];
  __shared__ float Bs[64][65];
  __shared__ float csred[4][64];
  int i0 = blockIdx.y * 64, j0 = blockIdx.x * 64;
  int t = threadIdx.x;
  for (int l = t; l < 1024; l += 256) {
    int r = l >> 4, c = (l & 15) << 2;
    float4 a = *reinterpret_cast<const float4*>(A + (size_t)(i0 + r) * D64 + c);
    As[r][c] = a.x; As[r][c + 1] = a.y; As[r][c + 2] = a.z; As[r][c + 3] = a.w;
    float4 b = *reinterpret_cast<const float4*>(B + (size_t)(j0 + r) * D64 + c);
    Bs[r][c] = b.x; Bs[r][c + 1] = b.y; Bs[r][c + 2] = b.z; Bs[r][c + 3] = b.w;
  }
  __syncthreads();
  int j = t & 63, rgrp = t >> 6;
  float acc[16];
#pragma unroll
  for (int ii = 0; ii < 16; ++ii) acc[ii] = 0.f;
  for (int k = 0; k < 64; ++k) {
    float bv = Bs[j][k];
#pragma unroll
    for (int ii = 0; ii < 16; ++ii) acc[ii] += As[rgrp * 16 + ii][k] * bv;
  }
  float cpart = 0.f;
#pragma unroll
  for (int ii = 0; ii < 16; ++ii) {
    float e = expf(acc[ii] * kTinv);
    S[(size_t)(i0 + rgrp * 16 + ii) * kNSH + j0 + j] = e;
    cpart += e;
    float rsum = e;
#pragma unroll
    for (int o = 32; o; o >>= 1) rsum += __shfl_xor(rsum, o);
    if (j == 0) atomicAdd(&rs[i0 + rgrp * 16 + ii], rsum);
  }
  csred[rgrp][j] = cpart;
  __syncthreads();
  if (t < 64) atomicAdd(&cs[j0 + t], csred[0][t] + csred[1][t] + csred[2][t] + csred[3][t]);
}

// ---------------- Ds[i] = sum_j S[i][j]*w[j] + 1 ----------------
__global__ void row_reduce_w1(const float* __restrict__ S, const float* __restrict__ w,
                              float* __restrict__ out) {
  int i = blockIdx.x;
  const float* row = S + (size_t)i * kNSH;
  float acc = 0.f;
  for (int j = threadIdx.x; j < kNSH; j += 256) acc += row[j] * w[j];
#pragma unroll
  for (int o = 32; o; o >>= 1) acc += __shfl_xor(acc, o);
  __shared__ float red[4];
  if ((threadIdx.x & 63) == 0) red[threadIdx.x >> 6] = acc;
  __syncthreads();
  if (threadIdx.x == 0) out[i] = red[0] + red[1] + red[2] + red[3] + 1.f;
}

// ---------------- Dt[j] = sum_i S[i][j]*w[i] + 1 (single pass, no atomics) ----------------
__global__ void col_reduce_w1(const float* __restrict__ S, const float* __restrict__ w,
                              float* __restrict__ out) {
  int j = blockIdx.x * 64 + (threadIdx.x & 63);
  int is = threadIdx.x >> 6;
  float acc = 0.f;
  for (int i = is; i < kNSH; i += 4) acc += S[(size_t)i * kNSH + j] * w[i];
  __shared__ float p[4][64];
  p[is][threadIdx.x & 63] = acc;
  __syncthreads();
  if (threadIdx.x < 64)
    out[blockIdx.x * 64 + threadIdx.x] =
        p[0][threadIdx.x] + p[1][threadIdx.x] + p[2][threadIdx.x] + p[3][threadIdx.x] + 1.f;
}

__global__ void init_rc(float* __restrict__ rs, float* __restrict__ cs) {
  int i = blockIdx.x * 256 + threadIdx.x;
  if (i < kNSH) { rs[i] = 0.f; cs[i] = 0.f; }
}

// ================= split-K tiled GEMM: part[slice] = op(S)_slice @ X =================
// TRANS=0: C[r][d] = sum_k S[r][k] X[k][d] ; TRANS=1: C[r][d] = sum_k S[k][r] X[k][d]
// tile 64x64, BK=32, K=4096 over 4 slices of 1024; thread = 4 rows x 4 cols.
template <int TRANS>
__global__ void gemmS(const float* __restrict__ A, const float* __restrict__ X,
                      float* __restrict__ part) {
  __shared__ float As[64][36];
  __shared__ float Xs[32][68];
  const int r0 = blockIdx.x * 64;
  const int k0base = blockIdx.y * 1024;
  const int t = threadIdx.x;
  const int rg4 = (t >> 4) << 2;   // row offset 0..60
  const int cg4 = (t & 15) << 2;   // col offset 0..60
  float acc[4][4];
#pragma unroll
  for (int a = 0; a < 4; ++a)
#pragma unroll
    for (int b = 0; b < 4; ++b) acc[a][b] = 0.f;

  for (int kt = 0; kt < 32; ++kt) {
    const int k0 = k0base + kt * 32;
    {  // stage X tile 32x64
      int kk = t >> 4;            // 0..15
      int cq = (t & 15) << 2;
#pragma unroll
      for (int p = 0; p < 2; ++p) {
        float4 xv = *reinterpret_cast<const float4*>(X + (size_t)(k0 + kk + p * 16) * D64 + cq);
        *reinterpret_cast<float4*>(&Xs[kk + p * 16][cq]) = xv;
      }
    }
    if (TRANS == 0) {  // A rows r0..r0+63, k k0..k0+31
      int r = t >> 3;             // 0..31
      int kq = (t & 7) << 2;
#pragma unroll
      for (int p = 0; p < 2; ++p) {
        float4 av = *reinterpret_cast<const float4*>(A + (size_t)(r0 + r + p * 32) * kNSH + k0 + kq);
        *reinterpret_cast<float4*>(&As[r + p * 32][kq]) = av;
      }
    } else {           // As[c][kk] = A[k0+kk][r0+c]
      int kk = t >> 4;            // 0..15
      int cq = (t & 15) << 2;
#pragma unroll
      for (int p = 0; p < 2; ++p) {
        float4 av = *reinterpret_cast<const float4*>(A + (size_t)(k0 + kk + p * 16) * kNSH + r0 + cq);
        As[cq + 0][kk + p * 16] = av.x;
        As[cq + 1][kk + p * 16] = av.y;
        As[cq + 2][kk + p * 16] = av.z;
        As[cq + 3][kk + p * 16] = av.w;
      }
    }
    __syncthreads();
#pragma unroll
    for (int k4 = 0; k4 < 32; k4 += 4) {
      float4 x0 = *reinterpret_cast<const float4*>(&Xs[k4 + 0][cg4]);
      float4 x1 = *reinterpret_cast<const float4*>(&Xs[k4 + 1][cg4]);
      float4 x2 = *reinterpret_cast<const float4*>(&Xs[k4 + 2][cg4]);
      float4 x3 = *reinterpret_cast<const float4*>(&Xs[k4 + 3][cg4]);
#pragma unroll
      for (int rr = 0; rr < 4; ++rr) {
        float4 a = *reinterpret_cast<const float4*>(&As[rg4 + rr][k4]);
        acc[rr][0] = fmaf(a.x, x0.x, fmaf(a.y, x1.x, fmaf(a.z, x2.x, fmaf(a.w, x3.x, acc[rr][0]))));
        acc[rr][1] = fmaf(a.x, x0.y, fmaf(a.y, x1.y, fmaf(a.z, x2.y, fmaf(a.w, x3.y, acc[rr][1]))));
        acc[rr][2] = fmaf(a.x, x0.z, fmaf(a.y, x1.z, fmaf(a.z, x2.z, fmaf(a.w, x3.z, acc[rr][2]))));
        acc[rr][3] = fmaf(a.x, x0.w, fmaf(a.y, x1.w, fmaf(a.z, x2.w, fmaf(a.w, x3.w, acc[rr][3]))));
      }
    }
    __syncthreads();
  }
  float* pp = part + ((size_t)blockIdx.y * kNSH + r0) * D64;
#pragma unroll
  for (int rr = 0; rr < 4; ++rr) {
    float4 v = make_float4(acc[rr][0], acc[rr][1], acc[rr][2], acc[rr][3]);
    *reinterpret_cast<float4*>(&pp[(size_t)(rg4 + rr) * D64 + cg4]) = v;
  }
}

// ================= split-K reduce + epilogue =================
// EPI 0: OUT = sum
// EPI 1: OUT = ADD + sum/max(SC[r],1e-12)
// EPI 2: OUT = l2n(relu((sum+ADD)/SC[r]))
// EPI 3: OUT2 = 0.5*(RAW + l2n(relu((sum+ADD)/SC[r])))
template <int EPI>
__global__ void red_epi(const float* __restrict__ part, const float* __restrict__ ADD,
                        const float* __restrict__ SC, float* __restrict__ OUT,
                        const float* __restrict__ RAW, float* __restrict__ OUT2) {
  int d = threadIdx.x & 63;
  int r = blockIdx.x * 4 + (threadIdx.x >> 6);
  size_t off = (size_t)r * D64 + d;
  const size_t SLICE = (size_t)kNSH * D64;
  float s = part[off] + part[SLICE + off] + part[2 * SLICE + off] + part[3 * SLICE + off];
  if (EPI == 0) { OUT[off] = s; return; }
  if (EPI == 1) { OUT[off] = ADD[off] + s / fmaxf(SC[r], 1e-12f); return; }
  float v = fmaxf((s + ADD[off]) / SC[r], 0.f);
  float ss = v * v;
#pragma unroll
  for (int o = 32; o; o >>= 1) ss += __shfl_xor(ss, o);
  v = v / fmaxf(sqrtf(ss), 1e-12f);
  if (EPI == 2) OUT[off] = v;
  else OUT2[off] = 0.5f * (RAW[off] + v);
}

extern "C" void kernel_launch(void* const* d_in, const int* in_sizes, int n_in,
                              void* d_out, int out_size, void* d_ws, size_t ws_size,
                              hipStream_t stream) {
  const float* src_user = (const float*)d_in[0];
  const float* tgt_user = (const float*)d_in[1];
  const float* src_item = (const float*)d_in[2];
  const float* tgt_item = (const float*)d_in[3];
  const float* mapping  = (const float*)d_in[4];
  const float* s_vals   = (const float*)d_in[5];
  const float* t_vals   = (const float*)d_in[6];
  const int*   s_idx    = (const int*)d_in[7];
  const int*   t_idx    = (const int*)d_in[8];
  float* out = (float*)d_out;

  float* w = (float*)d_ws;
  size_t o = 0;
  float* es1 = w + o; o += (size_t)kNS * D64;
  float* es2 = w + o; o += (size_t)kNS * D64;
  float* et1 = w + o; o += (size_t)kNT * D64;
  float* et2 = w + o; o += (size_t)kNT * D64;
  float* S    = w + o; o += (size_t)kNSH * kNSH;
  float* tmp  = w + o; o += (size_t)kNSH * D64;
  float* src2 = w + o; o += (size_t)kNSH * D64;
  float* tgt2 = w + o; o += (size_t)kNSH * D64;
  float* itS  = w + o; o += (size_t)kNSH * D64;
  float* itT  = w + o; o += (size_t)kNSH * D64;
  float* ybufA = w + o; o += (size_t)kNSH * D64;
  float* ybufB = w + o; o += (size_t)kNSH * D64;
  float* partA = w + o; o += (size_t)4 * kNSH * D64;
  float* partB = w + o; o += (size_t)4 * kNSH * D64;
  float* rs = w + o; o += kNSH;
  float* cs = w + o; o += kNSH;
  float* Ds = w + o; o += kNSH;
  float* Dt = w + o; o += kNSH;
  int* iw = (int*)(w + o);
  size_t io = 0;
  int* sPtr = iw + io; io += kNS;
  int* sEnd = iw + io; io += kNS;
  int* sCnt = iw + io; io += kNS;
  int* sCol = iw + io; io += kNNZ;
  int* tPtr = iw + io; io += kNT;
  int* tEnd = iw + io; io += kNT;
  int* tCnt = iw + io; io += kNT;
  int* tCol = iw + io; io += kNNZ;
  int* blk  = iw + io; io += 512;
  float* sVal = (float*)(iw + io); io += kNNZ;
  float* tVal = (float*)(iw + io); io += kNNZ;

  const int nbS = (kNS + kScanCh - 1) / kScanCh;
  const int nbT = (kNT + kScanCh - 1) / kScanCh;
  const int egrid = (kNNZ + 255) / 256;

  // ---- CSR build ----
  hipMemsetAsync(sCnt, 0, (size_t)kNS * 4, stream);
  hipMemsetAsync(tCnt, 0, (size_t)kNT * 4, stream);
  histo_kernel<<<egrid, 256, 0, stream>>>(s_idx, sCnt, kNNZ);
  histo_kernel<<<egrid, 256, 0, stream>>>(t_idx, tCnt, kNNZ);
  scan_pass1<<<nbS, 256, 0, stream>>>(sCnt, sPtr, blk, kNS);
  scan_pass2<<<1, 64, 0, stream>>>(blk, nbS);
  scan_pass3<<<nbS, 256, 0, stream>>>(sPtr, sEnd, blk, kNS);
  scan_pass1<<<nbT, 256, 0, stream>>>(tCnt, tPtr, blk, kNT);
  scan_pass2<<<1, 64, 0, stream>>>(blk, nbT);
  scan_pass3<<<nbT, 256, 0, stream>>>(tPtr, tEnd, blk, kNT);
  csr_scatter<<<egrid, 256, 0, stream>>>(s_idx, s_vals, sEnd, sCol, sVal, kNNZ);
  csr_scatter<<<egrid, 256, 0, stream>>>(t_idx, t_vals, tEnd, tCol, tVal, kNNZ);

  // ---- output col-block 0 (raw concat, no copies) ----
  raw_store<<<(kNS + 3) / 4, 256, 0, stream>>>(src_user, src_item, kNU, out, kNS, 0);
  raw_store<<<(kNT + 3) / 4, 256, 0, stream>>>(tgt_user, tgt_item, kNU, out, kNT, (size_t)kNS);

  // ---- layer 1 spmm (split-source gather) ----
  spmm_csr2<<<(kNS + 15) / 16, 256, 0, stream>>>(sPtr, sEnd, sCol, sVal, src_user, src_item, kNU, es1, kNS);
  spmm_csr2<<<(kNT + 15) / 16, 256, 0, stream>>>(tPtr, tEnd, tCol, tVal, tgt_user, tgt_item, kNU, et1, kNT);

  // ---- inter block ----
  init_rc<<<16, 256, 0, stream>>>(rs, cs);
  map_gemm<<<256, 256, 0, stream>>>(es1, mapping, tmp);
  gemm_exp_rc<<<dim3(64, 64), 256, 0, stream>>>(tmp, et1, S, rs, cs);
  row_reduce_w1<<<kNSH, 256, 0, stream>>>(S, cs, Ds);
  col_reduce_w1<<<64, 256, 0, stream>>>(S, rs, Dt);
  // src2 = src0 + (S @ tgt0)/rs
  gemmS<0><<<dim3(64, 4), 256, 0, stream>>>(S, et1, partA);
  red_epi<1><<<1024, 256, 0, stream>>>(partA, es1, rs, src2, nullptr, nullptr);
  // tgt2 = tgt0 + (S^T @ src2)/cs
  gemmS<1><<<dim3(64, 4), 256, 0, stream>>>(S, src2, partA);
  red_epi<1><<<1024, 256, 0, stream>>>(partA, et1, cs, tgt2, nullptr, nullptr);
  // 3 propagation iterations
  float* pa = src2; float* pb = itS;
  float* qa = tgt2; float* qb = itT;
  for (int itn = 0; itn < 3; ++itn) {
    gemmS<1><<<dim3(64, 4), 256, 0, stream>>>(S, pa, partA);   // y_s = S^T pa
    gemmS<0><<<dim3(64, 4), 256, 0, stream>>>(S, qa, partB);   // y_t = S qa
    red_epi<0><<<1024, 256, 0, stream>>>(partA, nullptr, nullptr, ybufA, nullptr, nullptr);
    red_epi<0><<<1024, 256, 0, stream>>>(partB, nullptr, nullptr, ybufB, nullptr, nullptr);
    gemmS<0><<<dim3(64, 4), 256, 0, stream>>>(S, ybufA, partA);
    gemmS<1><<<dim3(64, 4), 256, 0, stream>>>(S, ybufB, partB);
    if (itn < 2) {
      red_epi<2><<<1024, 256, 0, stream>>>(partA, pa, Ds, pb, nullptr, nullptr);
      red_epi<2><<<1024, 256, 0, stream>>>(partB, qa, Dt, qb, nullptr, nullptr);
      float* t0 = pa; pa = pb; pb = t0;
      float* t1 = qa; qa = qb; qb = t1;
    } else {  // final: emb[:4096] = 0.5*(raw + l2n(...)) written in place
      red_epi<3><<<1024, 256, 0, stream>>>(partA, pa, Ds, nullptr, es1, es1);
      red_epi<3><<<1024, 256, 0, stream>>>(partB, qa, Dt, nullptr, et1, et1);
    }
  }

  // ---- output col-block 1 ----
  l2n_store<<<(kNS + 3) / 4, 256, 0, stream>>>(es1, out, kNS, 0, 64);
  l2n_store<<<(kNT + 3) / 4, 256, 0, stream>>>(et1, out, kNT, (size_t)kNS, 64);

  // ---- layer 2 ----
  spmm_csr2<<<(kNS + 15) / 16, 256, 0, stream>>>(sPtr, sEnd, sCol, sVal, es1, es1, kNS, es2, kNS);
  spmm_csr2<<<(kNT + 15) / 16, 256, 0, stream>>>(tPtr, tEnd, tCol, tVal, et1, et1, kNT, et2, kNT);
  l2n_store<<<(kNS + 3) / 4, 256, 0, stream>>>(es2, out, kNS, 0, 128);
  l2n_store<<<(kNT + 3) / 4, 256, 0, stream>>>(et2, out, kNT, (size_t)kNS, 128);

  // ---- layer 3 ----
  spmm_csr2<<<(kNS + 15) / 16, 256, 0, stream>>>(sPtr, sEnd, sCol, sVal, es2, es2, kNS, es1, kNS);
  spmm_csr2<<<(kNT + 15) / 16, 256, 0, stream>>>(tPtr, tEnd, tCol, tVal, et2, et2, kNT, et1, kNT);
  l2n_store<<<(kNS + 3) / 4, 256, 0, stream>>>(es1, out, kNS, 0, 192);
  l2n_store<<<(kNT + 3) / 4, 256, 0, stream>>>(et1, out, kNT, (size_t)kNS, 192);
}

// Round 4
// 1618.532 us; speedup vs baseline: 8.7962x; 1.7118x over previous
//
#include <hip/hip_runtime.h>
#include <cstdint>
#include <cstddef>

typedef __attribute__((ext_vector_type(8))) short short8;
typedef __attribute__((ext_vector_type(8))) unsigned short ushort8;
typedef __attribute__((ext_vector_type(4))) float f32x4;

#define D64 64
static constexpr int kNU   = 215904;   // N_USERS
static constexpr int kNS   = 275904;   // N_S
static constexpr int kNT   = 265904;   // N_T
static constexpr int kNSH  = 4096;     // N_SHARED
static constexpr int kNNZ  = 2000000;
static constexpr float kTinv = 0.2f;   // 1/T
static constexpr int kScanCh = 2048;

__device__ __forceinline__ unsigned short f2bf(float x) {
  unsigned u = __builtin_bit_cast(unsigned, x);
  u += 0x7FFFu + ((u >> 16) & 1u);
  return (unsigned short)(u >> 16);
}
__device__ __forceinline__ float bf2f(unsigned short h) {
  return __builtin_bit_cast(float, (unsigned)h << 16);
}

// ================= CSR build =================
__global__ void histo_kernel(const int* __restrict__ idx, int* __restrict__ cnt, int nnz) {
  int e = blockIdx.x * 256 + threadIdx.x;
  if (e < nnz) atomicAdd(&cnt[idx[e]], 1);
}

__global__ void scan_pass1(const int* __restrict__ in, int* __restrict__ out,
                           int* __restrict__ blksum, int n) {
  __shared__ int ts[256];
  int base = blockIdx.x * kScanCh;
  int t = threadIdx.x;
  int local[8];
  int s = 0;
#pragma unroll
  for (int i = 0; i < 8; ++i) {
    int g = base + t * 8 + i;
    int v = (g < n) ? in[g] : 0;
    local[i] = s;
    s += v;
  }
  ts[t] = s;
  __syncthreads();
  for (int off = 1; off < 256; off <<= 1) {
    int v = (t >= off) ? ts[t - off] : 0;
    __syncthreads();
    ts[t] += v;
    __syncthreads();
  }
  int excl = (t == 0) ? 0 : ts[t - 1];
  if (t == 255) blksum[blockIdx.x] = ts[255];
#pragma unroll
  for (int i = 0; i < 8; ++i) {
    int g = base + t * 8 + i;
    if (g < n) out[g] = excl + local[i];
  }
}

__global__ void scan_pass2(int* __restrict__ blksum, int nb) {
  if (threadIdx.x == 0 && blockIdx.x == 0) {
    int s = 0;
    for (int i = 0; i < nb; ++i) { int v = blksum[i]; blksum[i] = s; s += v; }
  }
}

__global__ void scan_pass3(int* __restrict__ out, int* __restrict__ cursor,
                           const int* __restrict__ blksum, int n) {
  int base = blockIdx.x * kScanCh;
  int add = blksum[blockIdx.x];
  int t = threadIdx.x;
#pragma unroll
  for (int i = 0; i < 8; ++i) {
    int g = base + t * 8 + i;
    if (g < n) { int v = out[g] + add; out[g] = v; cursor[g] = v; }
  }
}

__global__ void csr_scatter(const int* __restrict__ idx, const float* __restrict__ vals,
                            int* __restrict__ cursor, int* __restrict__ cols,
                            float* __restrict__ vout, int nnz) {
  int e = blockIdx.x * 256 + threadIdx.x;
  if (e >= nnz) return;
  int r = idx[e];
  int p = atomicAdd(&cursor[r], 1);
  cols[p] = idx[nnz + e];
  vout[p] = vals[e];
}

// ======= gather SpMM (CSR), split source, fused l2n output store =======
__global__ void spmm_csr2(const int* __restrict__ row_ptr, const int* __restrict__ row_end,
                          const int* __restrict__ cols, const float* __restrict__ vals,
                          const float* __restrict__ x0, const float* __restrict__ x1, int n0,
                          float* __restrict__ y, int n,
                          float* __restrict__ out, size_t orow0, int coff, int skip_lo) {
  int r = blockIdx.x * 16 + (threadIdx.x >> 4);
  if (r >= n) return;
  int q = (threadIdx.x & 15) << 2;
  int beg = row_ptr[r], end = row_end[r];
  float4 acc = {0.f, 0.f, 0.f, 0.f};
  for (int i = beg; i < end; ++i) {
    int c = cols[i];
    float v = vals[i];
    const float* xp = (c < n0) ? (x0 + ((size_t)c << 6)) : (x1 + ((size_t)(c - n0) << 6));
    const float4 xv = *reinterpret_cast<const float4*>(xp + q);
    acc.x = fmaf(v, xv.x, acc.x);
    acc.y = fmaf(v, xv.y, acc.y);
    acc.z = fmaf(v, xv.z, acc.z);
    acc.w = fmaf(v, xv.w, acc.w);
  }
  *reinterpret_cast<float4*>(y + (size_t)r * D64 + q) = acc;
  // fused L2 normalize + strided out store (row group = 16 lanes)
  float ss = acc.x * acc.x + acc.y * acc.y + acc.z * acc.z + acc.w * acc.w;
  ss += __shfl_xor(ss, 1); ss += __shfl_xor(ss, 2);
  ss += __shfl_xor(ss, 4); ss += __shfl_xor(ss, 8);
  float inv = 1.f / fmaxf(sqrtf(ss), 1e-12f);
  if (r >= skip_lo) {
    float4 o = make_float4(acc.x * inv, acc.y * inv, acc.z * inv, acc.w * inv);
    *reinterpret_cast<float4*>(out + (orow0 + (size_t)r) * 256 + coff + q) = o;
  }
}

// ---------------- raw concat -> out col-block 0 ----------------
__global__ void raw_store(const float* __restrict__ a, const float* __restrict__ b, int n0,
                          float* __restrict__ out, int nrows, size_t row0) {
  int r = blockIdx.x * 4 + (threadIdx.x >> 6);
  if (r >= nrows) return;
  int d = threadIdx.x & 63;
  float v = (r < n0) ? a[(size_t)r * D64 + d] : b[(size_t)(r - n0) * D64 + d];
  out[(row0 + (size_t)r) * 256 + d] = v;
}

// ---------------- row-wise L2 normalize + strided store (small, shared rows) ----------------
__global__ void l2n_store(const float* __restrict__ in, float* __restrict__ out,
                          int nrows, size_t row0, int coff) {
  int r = blockIdx.x * 4 + (threadIdx.x >> 6);
  if (r >= nrows) return;
  int d = threadIdx.x & 63;
  float v = in[(size_t)r * D64 + d];
  float ss = v * v;
#pragma unroll
  for (int o = 32; o; o >>= 1) ss += __shfl_xor(ss, o);
  float n = fmaxf(sqrtf(ss), 1e-12f);
  out[(row0 + (size_t)r) * 256 + coff + d] = v / n;
}

// ---------------- tmp = src0 @ mapping (f32 compute, bf16 out) ----------------
__global__ void map_gemm(const float* __restrict__ A, const float* __restrict__ X,
                         unsigned short* __restrict__ Cb) {
  __shared__ float Xs[64][65];
  __shared__ float As[16][65];
  int r0 = blockIdx.x * 16;
  int t = threadIdx.x;
  int d = t & 63, rg = t >> 6;
  float acc[4] = {0.f, 0.f, 0.f, 0.f};
  for (int l = t; l < 1024; l += 256) {
    int r = l >> 4, c = (l & 15) << 2;
    float4 xv = *reinterpret_cast<const float4*>(X + (size_t)r * D64 + c);
    Xs[r][c] = xv.x; Xs[r][c + 1] = xv.y; Xs[r][c + 2] = xv.z; Xs[r][c + 3] = xv.w;
  }
  {
    int r = t >> 4, c = (t & 15) << 2;
    float4 av = *reinterpret_cast<const float4*>(A + (size_t)(r0 + r) * D64 + c);
    As[r][c] = av.x; As[r][c + 1] = av.y; As[r][c + 2] = av.z; As[r][c + 3] = av.w;
  }
  __syncthreads();
  for (int k = 0; k < 64; ++k) {
    float xv = Xs[k][d];
#pragma unroll
    for (int rr = 0; rr < 4; ++rr) acc[rr] += As[rg * 4 + rr][k] * xv;
  }
#pragma unroll
  for (int rr = 0; rr < 4; ++rr)
    Cb[(size_t)(r0 + rg * 4 + rr) * D64 + d] = f2bf(acc[rr]);
}

// ---------------- convert tgt0 (f32) -> row-major bf16 + transposed bf16 ----------------
__global__ void cvt_tgt(const float* __restrict__ in, unsigned short* __restrict__ rowmaj,
                        unsigned short* __restrict__ colmaj) {
  __shared__ unsigned short tile[64][72];
  int r0 = blockIdx.x * 64;
  int t = threadIdx.x;
  int r = t >> 2, cq = (t & 3) << 4;
  unsigned short buf[16] __attribute__((aligned(16)));
#pragma unroll
  for (int j = 0; j < 16; j += 4) {
    float4 v = *reinterpret_cast<const float4*>(in + (size_t)(r0 + r) * D64 + cq + j);
    buf[j] = f2bf(v.x); buf[j + 1] = f2bf(v.y); buf[j + 2] = f2bf(v.z); buf[j + 3] = f2bf(v.w);
  }
#pragma unroll
  for (int j = 0; j < 16; ++j) tile[r][cq + j] = buf[j];
  *reinterpret_cast<ushort8*>(&rowmaj[(size_t)(r0 + r) * D64 + cq]) =
      *reinterpret_cast<ushort8*>(&buf[0]);
  *reinterpret_cast<ushort8*>(&rowmaj[(size_t)(r0 + r) * D64 + cq + 8]) =
      *reinterpret_cast<ushort8*>(&buf[8]);
  __syncthreads();
  int c = t >> 2, rq = (t & 3) << 4;
#pragma unroll
  for (int j = 0; j < 16; ++j) buf[j] = tile[rq + j][c];
  *reinterpret_cast<ushort8*>(&colmaj[(size_t)c * kNSH + r0 + rq]) =
      *reinterpret_cast<ushort8*>(&buf[0]);
  *reinterpret_cast<ushort8*>(&colmaj[(size_t)c * kNSH + r0 + rq + 8]) =
      *reinterpret_cast<ushort8*>(&buf[8]);
}

__global__ void init_rc(float* __restrict__ rs, float* __restrict__ cs) {
  int i = blockIdx.x * 256 + threadIdx.x;
  if (i < kNSH) { rs[i] = 0.f; cs[i] = 0.f; }
}

// ======== MFMA: S=exp((tmp@tgt0^T)/T) -> Sbf, STbf (bf16), rs/cs (f32) ========
__global__ void expS_mfma(const unsigned short* __restrict__ Abf,
                          const unsigned short* __restrict__ Bbf,
                          unsigned short* __restrict__ Sbf, unsigned short* __restrict__ STbf,
                          float* __restrict__ rs, float* __restrict__ cs) {
  __shared__ unsigned short Cs[64][72];
  __shared__ float csred[4][64];
  int j0 = blockIdx.x * 64, i0 = blockIdx.y * 64;
  int t = threadIdx.x;
  int w = t >> 6, l = t & 63;
  int lr = l & 15, lk = (l >> 4) << 3;
  f32x4 acc[4] = {};
  const unsigned short* Ap = Abf + (size_t)(i0 + w * 16 + lr) * D64 + lk;
#pragma unroll
  for (int ks = 0; ks < 2; ++ks) {
    short8 a = *reinterpret_cast<const short8*>(Ap + ks * 32);
#pragma unroll
    for (int nt = 0; nt < 4; ++nt) {
      short8 b = *reinterpret_cast<const short8*>(
          Bbf + (size_t)(j0 + nt * 16 + lr) * D64 + ks * 32 + lk);
      acc[nt] = __builtin_amdgcn_mfma_f32_16x16x32_bf16(a, b, acc[nt], 0, 0, 0);
    }
  }
  float rowpart[4] = {0.f, 0.f, 0.f, 0.f};
#pragma unroll
  for (int nt = 0; nt < 4; ++nt) {
    float colpart = 0.f;
#pragma unroll
    for (int rg = 0; rg < 4; ++rg) {
      float e = __expf(acc[nt][rg] * kTinv);
      acc[nt][rg] = e;
      rowpart[rg] += e;
      colpart += e;
      Cs[w * 16 + (l >> 4) * 4 + rg][nt * 16 + lr] = f2bf(e);
    }
    float v = colpart;
    v += __shfl_xor(v, 16); v += __shfl_xor(v, 32);
    if (l < 16) csred[w][nt * 16 + l] = v;
  }
#pragma unroll
  for (int rg = 0; rg < 4; ++rg) {
    float v = rowpart[rg];
    v += __shfl_xor(v, 1); v += __shfl_xor(v, 2);
    v += __shfl_xor(v, 4); v += __shfl_xor(v, 8);
    if (lr == 0) atomicAdd(&rs[i0 + w * 16 + (l >> 4) * 4 + rg], v);
  }
  __syncthreads();
  if (t < 64) atomicAdd(&cs[j0 + t], csred[0][t] + csred[1][t] + csred[2][t] + csred[3][t]);
  // coalesced stores: S row-major, S^T via LDS transpose
  {
    int r = t >> 2, cq = (t & 3) << 4;
    ushort8 v0 = *reinterpret_cast<const ushort8*>(&Cs[r][cq]);
    ushort8 v1 = *reinterpret_cast<const ushort8*>(&Cs[r][cq + 8]);
    *reinterpret_cast<ushort8*>(&Sbf[(size_t)(i0 + r) * kNSH + j0 + cq]) = v0;
    *reinterpret_cast<ushort8*>(&Sbf[(size_t)(i0 + r) * kNSH + j0 + cq + 8]) = v1;
    int c = t >> 2, rq = (t & 3) << 4;
    unsigned short buf[16] __attribute__((aligned(16)));
#pragma unroll
    for (int j = 0; j < 16; ++j) buf[j] = Cs[rq + j][c];
    *reinterpret_cast<ushort8*>(&STbf[(size_t)(j0 + c) * kNSH + i0 + rq]) =
        *reinterpret_cast<ushort8*>(&buf[0]);
    *reinterpret_cast<ushort8*>(&STbf[(size_t)(j0 + c) * kNSH + i0 + rq + 8]) =
        *reinterpret_cast<ushort8*>(&buf[8]);
  }
}

// ---------------- out[i] = sum_j Sb[i][j]*w[j] + 1 (bf16 S, f32 accum) ----------------
__global__ void row_reduce_bf(const unsigned short* __restrict__ Sb, const float* __restrict__ w,
                              float* __restrict__ out) {
  int i = blockIdx.x;
  const unsigned short* row = Sb + (size_t)i * kNSH;
  int t = threadIdx.x;
  float acc = 0.f;
  for (int j0 = t * 8; j0 < kNSH; j0 += 2048) {
    short8 v = *reinterpret_cast<const short8*>(row + j0);
#pragma unroll
    for (int j = 0; j < 8; ++j) acc += bf2f((unsigned short)v[j]) * w[j0 + j];
  }
#pragma unroll
  for (int o = 32; o; o >>= 1) acc += __shfl_xor(acc, o);
  __shared__ float red[4];
  if ((t & 63) == 0) red[t >> 6] = acc;
  __syncthreads();
  if (t == 0) out[i] = red[0] + red[1] + red[2] + red[3] + 1.f;
}

// ======== dual-chain MFMA skinny GEMM: part = A(4096x4096 bf16) @ X(XT 64x4096 bf16) ========
__global__ void sgemm_bf(const unsigned short* __restrict__ aA, const unsigned short* __restrict__ xA,
                         float* __restrict__ pA,
                         const unsigned short* __restrict__ aB, const unsigned short* __restrict__ xB,
                         float* __restrict__ pB) {
  const unsigned short* A = (blockIdx.z == 0) ? aA : aB;
  const unsigned short* X = (blockIdx.z == 0) ? xA : xB;
  float* P = (blockIdx.z == 0) ? pA : pB;
  int t = threadIdx.x;
  int w = t >> 6, l = t & 63;
  int lr = l & 15, lk = (l >> 4) << 3;
  int m0 = blockIdx.x * 64 + w * 16;
  int k0 = blockIdx.y * 1024;
  f32x4 acc[4] = {};
  const unsigned short* Ap = A + (size_t)(m0 + lr) * kNSH + k0 + lk;
  const unsigned short* Xp = X + (size_t)lr * kNSH + k0 + lk;
  for (int ks = 0; ks < 32; ++ks) {
    short8 a = *reinterpret_cast<const short8*>(Ap + ks * 32);
#pragma unroll
    for (int nt = 0; nt < 4; ++nt) {
      short8 b = *reinterpret_cast<const short8*>(Xp + (size_t)nt * 16 * kNSH + ks * 32);
      acc[nt] = __builtin_amdgcn_mfma_f32_16x16x32_bf16(a, b, acc[nt], 0, 0, 0);
    }
  }
  float* Pp = P + ((size_t)blockIdx.y * kNSH + m0) * D64;
#pragma unroll
  for (int nt = 0; nt < 4; ++nt)
#pragma unroll
    for (int rg = 0; rg < 4; ++rg)
      Pp[(size_t)((l >> 4) * 4 + rg) * D64 + nt * 16 + lr] = acc[nt][rg];
}

// ======== split-K reduce + epilogue (dual-chain via blockIdx.y) ========
// EPI 0: outT = bf16(sum)                      (ybuf; no f32 out)
// EPI 1: out = ADD + sum/max(SC[r],1e-12); outT = bf16(out)
// EPI 2: out = l2n(relu((sum+ADD)/SC[r])); outT = bf16(out)
// EPI 3: out = 0.5*(RAW + l2n(relu((sum+ADD)/SC[r])))   (no outT)
template <int EPI>
__global__ void red_epi(const float* __restrict__ pA, const float* __restrict__ addA,
                        const float* __restrict__ scA, float* __restrict__ outA,
                        unsigned short* __restrict__ outTA, const float* __restrict__ rawA,
                        const float* __restrict__ pB, const float* __restrict__ addB,
                        const float* __restrict__ scB, float* __restrict__ outB,
                        unsigned short* __restrict__ outTB, const float* __restrict__ rawB) {
  const float* p = (blockIdx.y == 0) ? pA : pB;
  const float* add = (blockIdx.y == 0) ? addA : addB;
  const float* sc = (blockIdx.y == 0) ? scA : scB;
  float* out = (blockIdx.y == 0) ? outA : outB;
  unsigned short* outT = (blockIdx.y == 0) ? outTA : outTB;
  const float* raw = (blockIdx.y == 0) ? rawA : rawB;
  __shared__ unsigned short tile[64][4];
  int t = threadIdx.x;
  int d = t & 63, rl = t >> 6;
  int r = blockIdx.x * 4 + rl;
  size_t off = (size_t)r * D64 + d;
  const size_t SL = (size_t)kNSH * D64;
  float s = p[off] + p[SL + off] + p[2 * SL + off] + p[3 * SL + off];
  float v;
  if (EPI == 0) {
    v = s;
  } else if (EPI == 1) {
    v = add[off] + s / fmaxf(sc[r], 1e-12f);
    out[off] = v;
  } else {
    float x = fmaxf((s + add[off]) / sc[r], 0.f);
    float ss = x * x;
#pragma unroll
    for (int o = 32; o; o >>= 1) ss += __shfl_xor(ss, o);
    v = x / fmaxf(sqrtf(ss), 1e-12f);
    if (EPI == 2) out[off] = v;
    else out[off] = 0.5f * (raw[off] + v);
  }
  if (EPI != 3) {
    tile[d][rl] = f2bf(v);
    __syncthreads();
    if (t < 64) {
      unsigned long long pk;
      unsigned short* pp = reinterpret_cast<unsigned short*>(&pk);
      pp[0] = tile[t][0]; pp[1] = tile[t][1]; pp[2] = tile[t][2]; pp[3] = tile[t][3];
      *reinterpret_cast<unsigned long long*>(&outT[(size_t)t * kNSH + blockIdx.x * 4]) = pk;
    }
  }
}

extern "C" void kernel_launch(void* const* d_in, const int* in_sizes, int n_in,
                              void* d_out, int out_size, void* d_ws, size_t ws_size,
                              hipStream_t stream) {
  const float* src_user = (const float*)d_in[0];
  const float* tgt_user = (const float*)d_in[1];
  const float* src_item = (const float*)d_in[2];
  const float* tgt_item = (const float*)d_in[3];
  const float* mapping  = (const float*)d_in[4];
  const float* s_vals   = (const float*)d_in[5];
  const float* t_vals   = (const float*)d_in[6];
  const int*   s_idx    = (const int*)d_in[7];
  const int*   t_idx    = (const int*)d_in[8];
  float* out = (float*)d_out;

  float* w = (float*)d_ws;
  size_t o = 0;
  float* es1 = w + o; o += (size_t)kNS * D64;
  float* es2 = w + o; o += (size_t)kNS * D64;
  float* et1 = w + o; o += (size_t)kNT * D64;
  float* et2 = w + o; o += (size_t)kNT * D64;
  float* src2 = w + o; o += (size_t)kNSH * D64;
  float* tgt2 = w + o; o += (size_t)kNSH * D64;
  float* itS  = w + o; o += (size_t)kNSH * D64;
  float* itT  = w + o; o += (size_t)kNSH * D64;
  float* partA = w + o; o += (size_t)4 * kNSH * D64;
  float* partB = w + o; o += (size_t)4 * kNSH * D64;
  float* rs = w + o; o += kNSH;
  float* cs = w + o; o += kNSH;
  float* Ds = w + o; o += kNSH;
  float* Dt = w + o; o += kNSH;
  // bf16 region
  unsigned short* ub = (unsigned short*)(w + o);
  size_t uo = 0;
  unsigned short* Sbf   = ub + uo; uo += (size_t)kNSH * kNSH;
  unsigned short* STbf  = ub + uo; uo += (size_t)kNSH * kNSH;
  unsigned short* tmpbf = ub + uo; uo += (size_t)kNSH * D64;
  unsigned short* tgtbf = ub + uo; uo += (size_t)kNSH * D64;
  unsigned short* tgtT  = ub + uo; uo += (size_t)kNSH * D64;
  unsigned short* src2T = ub + uo; uo += (size_t)kNSH * D64;
  unsigned short* tgt2T = ub + uo; uo += (size_t)kNSH * D64;
  unsigned short* itST  = ub + uo; uo += (size_t)kNSH * D64;
  unsigned short* itTT  = ub + uo; uo += (size_t)kNSH * D64;
  unsigned short* ybAT  = ub + uo; uo += (size_t)kNSH * D64;
  unsigned short* ybBT  = ub + uo; uo += (size_t)kNSH * D64;
  // int region
  int* iw = (int*)(ub + uo + (uo & 1));
  size_t io = 0;
  int* sPtr = iw + io; io += kNS;
  int* sEnd = iw + io; io += kNS;
  int* sCnt = iw + io; io += kNS;
  int* sCol = iw + io; io += kNNZ;
  int* tPtr = iw + io; io += kNT;
  int* tEnd = iw + io; io += kNT;
  int* tCnt = iw + io; io += kNT;
  int* tCol = iw + io; io += kNNZ;
  int* blk  = iw + io; io += 512;
  float* sVal = (float*)(iw + io); io += kNNZ;
  float* tVal = (float*)(iw + io); io += kNNZ;

  const int nbS = (kNS + kScanCh - 1) / kScanCh;
  const int nbT = (kNT + kScanCh - 1) / kScanCh;
  const int egrid = (kNNZ + 255) / 256;

  // ---- CSR build ----
  hipMemsetAsync(sCnt, 0, (size_t)kNS * 4, stream);
  hipMemsetAsync(tCnt, 0, (size_t)kNT * 4, stream);
  histo_kernel<<<egrid, 256, 0, stream>>>(s_idx, sCnt, kNNZ);
  histo_kernel<<<egrid, 256, 0, stream>>>(t_idx, tCnt, kNNZ);
  scan_pass1<<<nbS, 256, 0, stream>>>(sCnt, sPtr, blk, kNS);
  scan_pass2<<<1, 64, 0, stream>>>(blk, nbS);
  scan_pass3<<<nbS, 256, 0, stream>>>(sPtr, sEnd, blk, kNS);
  scan_pass1<<<nbT, 256, 0, stream>>>(tCnt, tPtr, blk, kNT);
  scan_pass2<<<1, 64, 0, stream>>>(blk, nbT);
  scan_pass3<<<nbT, 256, 0, stream>>>(tPtr, tEnd, blk, kNT);
  csr_scatter<<<egrid, 256, 0, stream>>>(s_idx, s_vals, sEnd, sCol, sVal, kNNZ);
  csr_scatter<<<egrid, 256, 0, stream>>>(t_idx, t_vals, tEnd, tCol, tVal, kNNZ);

  // ---- out col-block 0 ----
  raw_store<<<(kNS + 3) / 4, 256, 0, stream>>>(src_user, src_item, kNU, out, kNS, 0);
  raw_store<<<(kNT + 3) / 4, 256, 0, stream>>>(tgt_user, tgt_item, kNU, out, kNT, (size_t)kNS);

  // ---- layer 1 spmm (+ out block 1 for rows >= 4096) ----
  spmm_csr2<<<(kNS + 15) / 16, 256, 0, stream>>>(sPtr, sEnd, sCol, sVal, src_user, src_item, kNU,
                                                 es1, kNS, out, 0, 64, kNSH);
  spmm_csr2<<<(kNT + 15) / 16, 256, 0, stream>>>(tPtr, tEnd, tCol, tVal, tgt_user, tgt_item, kNU,
                                                 et1, kNT, out, (size_t)kNS, 64, kNSH);

  // ---- inter block ----
  init_rc<<<16, 256, 0, stream>>>(rs, cs);
  map_gemm<<<256, 256, 0, stream>>>(es1, mapping, tmpbf);
  cvt_tgt<<<64, 256, 0, stream>>>(et1, tgtbf, tgtT);
  expS_mfma<<<dim3(64, 64), 256, 0, stream>>>(tmpbf, tgtbf, Sbf, STbf, rs, cs);
  row_reduce_bf<<<kNSH, 256, 0, stream>>>(Sbf, cs, Ds);
  row_reduce_bf<<<kNSH, 256, 0, stream>>>(STbf, rs, Dt);
  // src2 = src0 + (S@tgt0)/rs
  sgemm_bf<<<dim3(64, 4, 1), 256, 0, stream>>>(Sbf, tgtT, partA, Sbf, tgtT, partA);
  red_epi<1><<<dim3(1024, 1), 256, 0, stream>>>(partA, es1, rs, src2, src2T, nullptr,
                                                partA, es1, rs, src2, src2T, nullptr);
  // tgt2 = tgt0 + (S^T@src2)/cs
  sgemm_bf<<<dim3(64, 4, 1), 256, 0, stream>>>(STbf, src2T, partA, STbf, src2T, partA);
  red_epi<1><<<dim3(1024, 1), 256, 0, stream>>>(partA, et1, cs, tgt2, tgt2T, nullptr,
                                                partA, et1, cs, tgt2, tgt2T, nullptr);
  // 3 propagation iterations, dual-chain batched
  float* paF = src2; unsigned short* paT = src2T;
  float* pbF = itS;  unsigned short* pbT = itST;
  float* qaF = tgt2; unsigned short* qaT = tgt2T;
  float* qbF = itT;  unsigned short* qbT = itTT;
  for (int itn = 0; itn < 3; ++itn) {
    sgemm_bf<<<dim3(64, 4, 2), 256, 0, stream>>>(STbf, paT, partA, Sbf, qaT, partB);
    red_epi<0><<<dim3(1024, 2), 256, 0, stream>>>(partA, nullptr, nullptr, nullptr, ybAT, nullptr,
                                                  partB, nullptr, nullptr, nullptr, ybBT, nullptr);
    sgemm_bf<<<dim3(64, 4, 2), 256, 0, stream>>>(Sbf, ybAT, partA, STbf, ybBT, partB);
    if (itn < 2) {
      red_epi<2><<<dim3(1024, 2), 256, 0, stream>>>(partA, paF, Ds, pbF, pbT, nullptr,
                                                    partB, qaF, Dt, qbF, qbT, nullptr);
      float* tf = paF; paF = pbF; pbF = tf;
      unsigned short* tt = paT; paT = pbT; pbT = tt;
      tf = qaF; qaF = qbF; qbF = tf;
      tt = qaT; qaT = qbT; qbT = tt;
    } else {
      red_epi<3><<<dim3(1024, 2), 256, 0, stream>>>(partA, paF, Ds, es1, nullptr, es1,
                                                    partB, qaF, Dt, et1, nullptr, et1);
    }
  }
  // out block 1, shared rows (post-inter)
  l2n_store<<<kNSH / 4, 256, 0, stream>>>(es1, out, kNSH, 0, 64);
  l2n_store<<<kNSH / 4, 256, 0, stream>>>(et1, out, kNSH, (size_t)kNS, 64);

  // ---- layer 2 ----
  spmm_csr2<<<(kNS + 15) / 16, 256, 0, stream>>>(sPtr, sEnd, sCol, sVal, es1, es1, kNS,
                                                 es2, kNS, out, 0, 128, 0);
  spmm_csr2<<<(kNT + 15) / 16, 256, 0, stream>>>(tPtr, tEnd, tCol, tVal, et1, et1, kNT,
                                                 et2, kNT, out, (size_t)kNS, 128, 0);
  // ---- layer 3 ----
  spmm_csr2<<<(kNS + 15) / 16, 256, 0, stream>>>(sPtr, sEnd, sCol, sVal, es2, es2, kNS,
                                                 es1, kNS, out, 0, 192, 0);
  spmm_csr2<<<(kNT + 15) / 16, 256, 0, stream>>>(tPtr, tEnd, tCol, tVal, et2, et2, kNT,
                                                 et1, kNT, out, (size_t)kNS, 192, 0);
}

// Round 5
// 1236.275 us; speedup vs baseline: 11.5159x; 1.3092x over previous
//
#include <hip/hip_runtime.h>
#include <cstdint>
#include <cstddef>

typedef __attribute__((ext_vector_type(8))) short short8;
typedef __attribute__((ext_vector_type(8))) unsigned short ushort8;
typedef __attribute__((ext_vector_type(4))) float f32x4;

#define D64 64
static constexpr int kNU   = 215904;   // N_USERS
static constexpr int kNS   = 275904;   // N_S
static constexpr int kNT   = 265904;   // N_T
static constexpr int kNSH  = 4096;     // N_SHARED
static constexpr int kNNZ  = 2000000;
static constexpr float kTinv = 0.2f;   // 1/T
static constexpr int kScanCh = 2048;
static constexpr int kNbS = (kNS + kScanCh - 1) / kScanCh;  // 135
static constexpr int kNbT = (kNT + kScanCh - 1) / kScanCh;  // 130

__device__ __forceinline__ unsigned short f2bf(float x) {
  unsigned u = __builtin_bit_cast(unsigned, x);
  u += 0x7FFFu + ((u >> 16) & 1u);
  return (unsigned short)(u >> 16);
}
__device__ __forceinline__ float bf2f(unsigned short h) {
  return __builtin_bit_cast(float, (unsigned)h << 16);
}

// ================= init: zero counters + rs/cs =================
__global__ void init_misc(int* __restrict__ sCnt, int* __restrict__ tCnt,
                          float* __restrict__ rs, float* __restrict__ cs) {
  int i = blockIdx.x * 256 + threadIdx.x;
  if (i < kNS) sCnt[i] = 0;
  if (i < kNT) tCnt[i] = 0;
  if (i < kNSH) { rs[i] = 0.f; cs[i] = 0.f; }
}

// ================= CSR build (merged s/t via blockIdx.y) =================
__global__ void histo2(const int* __restrict__ s_idx, const int* __restrict__ t_idx,
                       int* __restrict__ sCnt, int* __restrict__ tCnt) {
  int e = blockIdx.x * 256 + threadIdx.x;
  const int* idx = blockIdx.y ? t_idx : s_idx;
  int* cnt = blockIdx.y ? tCnt : sCnt;
  if (e < kNNZ) atomicAdd(&cnt[idx[e]], 1);
}

__global__ void scan1m(const int* __restrict__ sCnt, int* __restrict__ sPtr,
                       const int* __restrict__ tCnt, int* __restrict__ tPtr,
                       int* __restrict__ blk) {
  int n = blockIdx.y ? kNT : kNS;
  int base = blockIdx.x * kScanCh;
  if (base >= n) return;
  const int* in = blockIdx.y ? tCnt : sCnt;
  int* outp = blockIdx.y ? tPtr : sPtr;
  int* bs = blk + blockIdx.y * 512;
  __shared__ int ts[256];
  int t = threadIdx.x;
  int local[8];
  int s = 0;
#pragma unroll
  for (int i = 0; i < 8; ++i) {
    int g = base + t * 8 + i;
    int v = (g < n) ? in[g] : 0;
    local[i] = s;
    s += v;
  }
  ts[t] = s;
  __syncthreads();
  for (int off = 1; off < 256; off <<= 1) {
    int v = (t >= off) ? ts[t - off] : 0;
    __syncthreads();
    ts[t] += v;
    __syncthreads();
  }
  int excl = (t == 0) ? 0 : ts[t - 1];
  if (t == 255) bs[blockIdx.x] = ts[255];
#pragma unroll
  for (int i = 0; i < 8; ++i) {
    int g = base + t * 8 + i;
    if (g < n) outp[g] = excl + local[i];
  }
}

__global__ void scan2m(int* __restrict__ blk) {
  int t = threadIdx.x;
  if (t == 0) { int s = 0; for (int i = 0; i < kNbS; ++i) { int v = blk[i]; blk[i] = s; s += v; } }
  if (t == 64) { int s = 0; for (int i = 0; i < kNbT; ++i) { int v = blk[512 + i]; blk[512 + i] = s; s += v; } }
}

__global__ void scan3m(int* __restrict__ sPtr, int* __restrict__ sCur,
                       int* __restrict__ tPtr, int* __restrict__ tCur,
                       const int* __restrict__ blk) {
  int n = blockIdx.y ? kNT : kNS;
  int base = blockIdx.x * kScanCh;
  if (base >= n) return;
  int* outp = blockIdx.y ? tPtr : sPtr;
  int* cur = blockIdx.y ? tCur : sCur;
  int add = blk[blockIdx.y * 512 + blockIdx.x];
  int t = threadIdx.x;
#pragma unroll
  for (int i = 0; i < 8; ++i) {
    int g = base + t * 8 + i;
    if (g < n) { int v = outp[g] + add; outp[g] = v; cur[g] = v; }
  }
}

__global__ void scatter2(const int* __restrict__ s_idx, const float* __restrict__ s_vals,
                         int* __restrict__ sCur, int2* __restrict__ sEV,
                         const int* __restrict__ t_idx, const float* __restrict__ t_vals,
                         int* __restrict__ tCur, int2* __restrict__ tEV) {
  int e = blockIdx.x * 256 + threadIdx.x;
  if (e >= kNNZ) return;
  const int* idx = blockIdx.y ? t_idx : s_idx;
  const float* vals = blockIdx.y ? t_vals : s_vals;
  int* cur = blockIdx.y ? tCur : sCur;
  int2* EV = blockIdx.y ? tEV : sEV;
  int r = idx[e];
  int p = atomicAdd(&cur[r], 1);
  EV[p] = make_int2(idx[kNNZ + e], __float_as_int(vals[e]));
}

// ====== layer-1 SpMM: f32 gathers, fused raw-store (block 0) + l2n out (block 1, r>=4096) ======
__global__ void spmm1(const int* __restrict__ sPtr, const int* __restrict__ sCur,
                      const int2* __restrict__ sEV,
                      const int* __restrict__ tPtr, const int* __restrict__ tCur,
                      const int2* __restrict__ tEV,
                      const float* __restrict__ su, const float* __restrict__ si,
                      const float* __restrict__ tu, const float* __restrict__ ti,
                      float* __restrict__ es1h, float* __restrict__ et1h,
                      unsigned short* __restrict__ es1b, unsigned short* __restrict__ et1b,
                      float* __restrict__ out) {
  int g = blockIdx.x * 16 + (threadIdx.x >> 4);
  bool isS = g < kNS;
  int r = isS ? g : g - kNS;
  if (!isS && r >= kNT) return;
  const int* Pp = isS ? sPtr : tPtr;
  const int* Pc = isS ? sCur : tCur;
  const int2* EV = isS ? sEV : tEV;
  const float* xu = isS ? su : tu;
  const float* xi = isS ? si : ti;
  int q = (threadIdx.x & 15) << 2;
  // fused raw concat store (out col-block 0)
  {
    const float4 rv = *reinterpret_cast<const float4*>(
        (r < kNU) ? (xu + ((size_t)r << 6) + q) : (xi + ((size_t)(r - kNU) << 6) + q));
    *reinterpret_cast<float4*>(out + (size_t)g * 256 + q) = rv;
  }
  int beg = Pp[r], end = Pc[r];
  float4 acc = {0.f, 0.f, 0.f, 0.f};
  int i = beg;
  for (; i + 2 <= end; i += 2) {
    int2 e0 = EV[i], e1 = EV[i + 1];
    const float* p0 = (e0.x < kNU) ? (xu + ((size_t)e0.x << 6)) : (xi + ((size_t)(e0.x - kNU) << 6));
    const float* p1 = (e1.x < kNU) ? (xu + ((size_t)e1.x << 6)) : (xi + ((size_t)(e1.x - kNU) << 6));
    float4 x0 = *reinterpret_cast<const float4*>(p0 + q);
    float4 x1 = *reinterpret_cast<const float4*>(p1 + q);
    float v0 = __int_as_float(e0.y), v1 = __int_as_float(e1.y);
    acc.x = fmaf(v0, x0.x, fmaf(v1, x1.x, acc.x));
    acc.y = fmaf(v0, x0.y, fmaf(v1, x1.y, acc.y));
    acc.z = fmaf(v0, x0.z, fmaf(v1, x1.z, acc.z));
    acc.w = fmaf(v0, x0.w, fmaf(v1, x1.w, acc.w));
  }
  if (i < end) {
    int2 e0 = EV[i];
    const float* p0 = (e0.x < kNU) ? (xu + ((size_t)e0.x << 6)) : (xi + ((size_t)(e0.x - kNU) << 6));
    float4 x0 = *reinterpret_cast<const float4*>(p0 + q);
    float v0 = __int_as_float(e0.y);
    acc.x = fmaf(v0, x0.x, acc.x);
    acc.y = fmaf(v0, x0.y, acc.y);
    acc.z = fmaf(v0, x0.z, acc.z);
    acc.w = fmaf(v0, x0.w, acc.w);
  }
  // f32 head (rows < 4096 feed the inter block)
  if (r < kNSH) {
    float* eh = isS ? es1h : et1h;
    *reinterpret_cast<float4*>(eh + ((size_t)r << 6) + q) = acc;
  }
  // bf16 full copy (layer-2 gather source)
  {
    unsigned short* eb = isS ? es1b : et1b;
    unsigned long long pk = (unsigned long long)f2bf(acc.x) |
                            ((unsigned long long)f2bf(acc.y) << 16) |
                            ((unsigned long long)f2bf(acc.z) << 32) |
                            ((unsigned long long)f2bf(acc.w) << 48);
    *reinterpret_cast<unsigned long long*>(eb + ((size_t)r << 6) + q) = pk;
  }
  // l2n + out block 1 for non-shared rows
  float ss = acc.x * acc.x + acc.y * acc.y + acc.z * acc.z + acc.w * acc.w;
  ss += __shfl_xor(ss, 1); ss += __shfl_xor(ss, 2);
  ss += __shfl_xor(ss, 4); ss += __shfl_xor(ss, 8);
  float inv = 1.f / fmaxf(sqrtf(ss), 1e-12f);
  if (r >= kNSH) {
    float4 o = make_float4(acc.x * inv, acc.y * inv, acc.z * inv, acc.w * inv);
    *reinterpret_cast<float4*>(out + (size_t)g * 256 + 64 + q) = o;
  }
}

// ====== layers 2/3 SpMM: bf16 gathers (8-lane groups), fused l2n out store ======
template <int WRITE_Y>
__global__ void spmm23(const int* __restrict__ sPtr, const int* __restrict__ sCur,
                       const int2* __restrict__ sEV,
                       const int* __restrict__ tPtr, const int* __restrict__ tCur,
                       const int2* __restrict__ tEV,
                       const unsigned short* __restrict__ xs, const unsigned short* __restrict__ xt,
                       unsigned short* __restrict__ ys, unsigned short* __restrict__ yt,
                       float* __restrict__ out, int coff) {
  int g = blockIdx.x * 32 + (threadIdx.x >> 3);
  bool isS = g < kNS;
  int r = isS ? g : g - kNS;
  if (!isS && r >= kNT) return;
  const int* Pp = isS ? sPtr : tPtr;
  const int* Pc = isS ? sCur : tCur;
  const int2* EV = isS ? sEV : tEV;
  const unsigned short* xb = isS ? xs : xt;
  int q = (threadIdx.x & 7) << 3;
  int beg = Pp[r], end = Pc[r];
  float acc[8] = {0.f, 0.f, 0.f, 0.f, 0.f, 0.f, 0.f, 0.f};
  int i = beg;
  for (; i + 2 <= end; i += 2) {
    int2 e0 = EV[i], e1 = EV[i + 1];
    ushort8 x0 = *reinterpret_cast<const ushort8*>(xb + ((size_t)e0.x << 6) + q);
    ushort8 x1 = *reinterpret_cast<const ushort8*>(xb + ((size_t)e1.x << 6) + q);
    float v0 = __int_as_float(e0.y), v1 = __int_as_float(e1.y);
#pragma unroll
    for (int j = 0; j < 8; ++j)
      acc[j] = fmaf(v0, bf2f((unsigned short)x0[j]), fmaf(v1, bf2f((unsigned short)x1[j]), acc[j]));
  }
  if (i < end) {
    int2 e0 = EV[i];
    ushort8 x0 = *reinterpret_cast<const ushort8*>(xb + ((size_t)e0.x << 6) + q);
    float v0 = __int_as_float(e0.y);
#pragma unroll
    for (int j = 0; j < 8; ++j) acc[j] = fmaf(v0, bf2f((unsigned short)x0[j]), acc[j]);
  }
  if (WRITE_Y) {
    unsigned short* yb = isS ? ys : yt;
    ushort8 o;
#pragma unroll
    for (int j = 0; j < 8; ++j) o[j] = f2bf(acc[j]);
    *reinterpret_cast<ushort8*>(yb + ((size_t)r << 6) + q) = o;
  }
  float ss = 0.f;
#pragma unroll
  for (int j = 0; j < 8; ++j) ss += acc[j] * acc[j];
  ss += __shfl_xor(ss, 1); ss += __shfl_xor(ss, 2); ss += __shfl_xor(ss, 4);
  float inv = 1.f / fmaxf(sqrtf(ss), 1e-12f);
  float* op = out + (size_t)g * 256 + coff + q;
  *reinterpret_cast<float4*>(op) = make_float4(acc[0] * inv, acc[1] * inv, acc[2] * inv, acc[3] * inv);
  *reinterpret_cast<float4*>(op + 4) = make_float4(acc[4] * inv, acc[5] * inv, acc[6] * inv, acc[7] * inv);
}

// ---------------- merged: tmp = src0@mapping (bf16 out) | cvt tgt0 -> bf16 row+col ----------------
__global__ void prep_inter(const float* __restrict__ A, const float* __restrict__ M,
                           unsigned short* __restrict__ tmpbf,
                           const float* __restrict__ Tg, unsigned short* __restrict__ rowmaj,
                           unsigned short* __restrict__ colmaj) {
  int t = threadIdx.x;
  if (blockIdx.y == 0) {
    __shared__ float Xs[64][65];
    __shared__ float As[16][65];
    int r0 = blockIdx.x * 16;
    int d = t & 63, rg = t >> 6;
    float acc[4] = {0.f, 0.f, 0.f, 0.f};
    for (int l = t; l < 1024; l += 256) {
      int r = l >> 4, c = (l & 15) << 2;
      float4 xv = *reinterpret_cast<const float4*>(M + (size_t)r * D64 + c);
      Xs[r][c] = xv.x; Xs[r][c + 1] = xv.y; Xs[r][c + 2] = xv.z; Xs[r][c + 3] = xv.w;
    }
    {
      int r = t >> 4, c = (t & 15) << 2;
      float4 av = *reinterpret_cast<const float4*>(A + (size_t)(r0 + r) * D64 + c);
      As[r][c] = av.x; As[r][c + 1] = av.y; As[r][c + 2] = av.z; As[r][c + 3] = av.w;
    }
    __syncthreads();
    for (int k = 0; k < 64; ++k) {
      float xv = Xs[k][d];
#pragma unroll
      for (int rr = 0; rr < 4; ++rr) acc[rr] += As[rg * 4 + rr][k] * xv;
    }
#pragma unroll
    for (int rr = 0; rr < 4; ++rr)
      tmpbf[(size_t)(r0 + rg * 4 + rr) * D64 + d] = f2bf(acc[rr]);
  } else {
    if (blockIdx.x >= 64) return;
    __shared__ unsigned short tile[64][72];
    int r0 = blockIdx.x * 64;
    int r = t >> 2, cq = (t & 3) << 4;
    unsigned short buf[16] __attribute__((aligned(16)));
#pragma unroll
    for (int j = 0; j < 16; j += 4) {
      float4 v = *reinterpret_cast<const float4*>(Tg + (size_t)(r0 + r) * D64 + cq + j);
      buf[j] = f2bf(v.x); buf[j + 1] = f2bf(v.y); buf[j + 2] = f2bf(v.z); buf[j + 3] = f2bf(v.w);
    }
#pragma unroll
    for (int j = 0; j < 16; ++j) tile[r][cq + j] = buf[j];
    *reinterpret_cast<ushort8*>(&rowmaj[(size_t)(r0 + r) * D64 + cq]) =
        *reinterpret_cast<ushort8*>(&buf[0]);
    *reinterpret_cast<ushort8*>(&rowmaj[(size_t)(r0 + r) * D64 + cq + 8]) =
        *reinterpret_cast<ushort8*>(&buf[8]);
    __syncthreads();
    int c = t >> 2, rq = (t & 3) << 4;
#pragma unroll
    for (int j = 0; j < 16; ++j) buf[j] = tile[rq + j][c];
    *reinterpret_cast<ushort8*>(&colmaj[(size_t)c * kNSH + r0 + rq]) =
        *reinterpret_cast<ushort8*>(&buf[0]);
    *reinterpret_cast<ushort8*>(&colmaj[(size_t)c * kNSH + r0 + rq + 8]) =
        *reinterpret_cast<ushort8*>(&buf[8]);
  }
}

// ======== MFMA: S=exp((tmp@tgt0^T)/T) -> Sbf, STbf (bf16), rs/cs (f32) ========
__global__ void expS_mfma(const unsigned short* __restrict__ Abf,
                          const unsigned short* __restrict__ Bbf,
                          unsigned short* __restrict__ Sbf, unsigned short* __restrict__ STbf,
                          float* __restrict__ rs, float* __restrict__ cs) {
  __shared__ unsigned short Cs[64][72];
  __shared__ float csred[4][64];
  int j0 = blockIdx.x * 64, i0 = blockIdx.y * 64;
  int t = threadIdx.x;
  int w = t >> 6, l = t & 63;
  int lr = l & 15, lk = (l >> 4) << 3;
  f32x4 acc[4] = {};
  const unsigned short* Ap = Abf + (size_t)(i0 + w * 16 + lr) * D64 + lk;
#pragma unroll
  for (int ks = 0; ks < 2; ++ks) {
    short8 a = *reinterpret_cast<const short8*>(Ap + ks * 32);
#pragma unroll
    for (int nt = 0; nt < 4; ++nt) {
      short8 b = *reinterpret_cast<const short8*>(
          Bbf + (size_t)(j0 + nt * 16 + lr) * D64 + ks * 32 + lk);
      acc[nt] = __builtin_amdgcn_mfma_f32_16x16x32_bf16(a, b, acc[nt], 0, 0, 0);
    }
  }
  float rowpart[4] = {0.f, 0.f, 0.f, 0.f};
#pragma unroll
  for (int nt = 0; nt < 4; ++nt) {
    float colpart = 0.f;
#pragma unroll
    for (int rg = 0; rg < 4; ++rg) {
      float e = __expf(acc[nt][rg] * kTinv);
      acc[nt][rg] = e;
      rowpart[rg] += e;
      colpart += e;
      Cs[w * 16 + (l >> 4) * 4 + rg][nt * 16 + lr] = f2bf(e);
    }
    float v = colpart;
    v += __shfl_xor(v, 16); v += __shfl_xor(v, 32);
    if (l < 16) csred[w][nt * 16 + l] = v;
  }
#pragma unroll
  for (int rg = 0; rg < 4; ++rg) {
    float v = rowpart[rg];
    v += __shfl_xor(v, 1); v += __shfl_xor(v, 2);
    v += __shfl_xor(v, 4); v += __shfl_xor(v, 8);
    if (lr == 0) atomicAdd(&rs[i0 + w * 16 + (l >> 4) * 4 + rg], v);
  }
  __syncthreads();
  if (t < 64) atomicAdd(&cs[j0 + t], csred[0][t] + csred[1][t] + csred[2][t] + csred[3][t]);
  {
    int r = t >> 2, cq = (t & 3) << 4;
    ushort8 v0 = *reinterpret_cast<const ushort8*>(&Cs[r][cq]);
    ushort8 v1 = *reinterpret_cast<const ushort8*>(&Cs[r][cq + 8]);
    *reinterpret_cast<ushort8*>(&Sbf[(size_t)(i0 + r) * kNSH + j0 + cq]) = v0;
    *reinterpret_cast<ushort8*>(&Sbf[(size_t)(i0 + r) * kNSH + j0 + cq + 8]) = v1;
    int c = t >> 2, rq = (t & 3) << 4;
    unsigned short buf[16] __attribute__((aligned(16)));
#pragma unroll
    for (int j = 0; j < 16; ++j) buf[j] = Cs[rq + j][c];
    *reinterpret_cast<ushort8*>(&STbf[(size_t)(j0 + c) * kNSH + i0 + rq]) =
        *reinterpret_cast<ushort8*>(&buf[0]);
    *reinterpret_cast<ushort8*>(&STbf[(size_t)(j0 + c) * kNSH + i0 + rq + 8]) =
        *reinterpret_cast<ushort8*>(&buf[8]);
  }
}

// ---- merged Ds/Dt: y=0 -> Ds[i]=sum Sbf[i][j]*cs[j]+1; y=1 -> Dt[i]=sum STbf[i][j]*rs[j]+1 ----
__global__ void rowred2(const unsigned short* __restrict__ Sbf, const float* __restrict__ cs,
                        float* __restrict__ Ds,
                        const unsigned short* __restrict__ STbf, const float* __restrict__ rs,
                        float* __restrict__ Dt) {
  const unsigned short* Sb = blockIdx.y ? STbf : Sbf;
  const float* w = blockIdx.y ? rs : cs;
  float* outp = blockIdx.y ? Dt : Ds;
  int i = blockIdx.x;
  const unsigned short* row = Sb + (size_t)i * kNSH;
  int t = threadIdx.x;
  float acc = 0.f;
  for (int j0 = t * 8; j0 < kNSH; j0 += 2048) {
    short8 v = *reinterpret_cast<const short8*>(row + j0);
#pragma unroll
    for (int j = 0; j < 8; ++j) acc += bf2f((unsigned short)v[j]) * w[j0 + j];
  }
#pragma unroll
  for (int o = 32; o; o >>= 1) acc += __shfl_xor(acc, o);
  __shared__ float red[4];
  if ((t & 63) == 0) red[t >> 6] = acc;
  __syncthreads();
  if (t == 0) outp[i] = red[0] + red[1] + red[2] + red[3] + 1.f;
}

// ======== dual-chain MFMA skinny GEMM ========
__global__ void sgemm_bf(const unsigned short* __restrict__ aA, const unsigned short* __restrict__ xA,
                         float* __restrict__ pA,
                         const unsigned short* __restrict__ aB, const unsigned short* __restrict__ xB,
                         float* __restrict__ pB) {
  const unsigned short* A = (blockIdx.z == 0) ? aA : aB;
  const unsigned short* X = (blockIdx.z == 0) ? xA : xB;
  float* P = (blockIdx.z == 0) ? pA : pB;
  int t = threadIdx.x;
  int w = t >> 6, l = t & 63;
  int lr = l & 15, lk = (l >> 4) << 3;
  int m0 = blockIdx.x * 64 + w * 16;
  int k0 = blockIdx.y * 1024;
  f32x4 acc[4] = {};
  const unsigned short* Ap = A + (size_t)(m0 + lr) * kNSH + k0 + lk;
  const unsigned short* Xp = X + (size_t)lr * kNSH + k0 + lk;
  for (int ks = 0; ks < 32; ++ks) {
    short8 a = *reinterpret_cast<const short8*>(Ap + ks * 32);
#pragma unroll
    for (int nt = 0; nt < 4; ++nt) {
      short8 b = *reinterpret_cast<const short8*>(Xp + (size_t)nt * 16 * kNSH + ks * 32);
      acc[nt] = __builtin_amdgcn_mfma_f32_16x16x32_bf16(a, b, acc[nt], 0, 0, 0);
    }
  }
  float* Pp = P + ((size_t)blockIdx.y * kNSH + m0) * D64;
#pragma unroll
  for (int nt = 0; nt < 4; ++nt)
#pragma unroll
    for (int rg = 0; rg < 4; ++rg)
      Pp[(size_t)((l >> 4) * 4 + rg) * D64 + nt * 16 + lr] = acc[nt][rg];
}

// ======== split-K reduce + epilogue (dual-chain via blockIdx.y) ========
// EPI 0: outT = bf16(sum)
// EPI 1: out = ADD + sum/max(SC,eps); outT = bf16
// EPI 2: out = l2n(relu((sum+ADD)/SC)); outT = bf16
// EPI 3: out = 0.5*(RAW + l2n(relu((sum+ADD)/SC))); RM = bf16(out) row-major
template <int EPI>
__global__ void red_epi(const float* __restrict__ pA, const float* __restrict__ addA,
                        const float* __restrict__ scA, float* __restrict__ outA,
                        unsigned short* __restrict__ outTA, const float* __restrict__ rawA,
                        unsigned short* __restrict__ rmA,
                        const float* __restrict__ pB, const float* __restrict__ addB,
                        const float* __restrict__ scB, float* __restrict__ outB,
                        unsigned short* __restrict__ outTB, const float* __restrict__ rawB,
                        unsigned short* __restrict__ rmB) {
  const float* p = (blockIdx.y == 0) ? pA : pB;
  const float* add = (blockIdx.y == 0) ? addA : addB;
  const float* sc = (blockIdx.y == 0) ? scA : scB;
  float* out = (blockIdx.y == 0) ? outA : outB;
  unsigned short* outT = (blockIdx.y == 0) ? outTA : outTB;
  const float* raw = (blockIdx.y == 0) ? rawA : rawB;
  unsigned short* rm = (blockIdx.y == 0) ? rmA : rmB;
  __shared__ unsigned short tile[64][4];
  int t = threadIdx.x;
  int d = t & 63, rl = t >> 6;
  int r = blockIdx.x * 4 + rl;
  size_t off = (size_t)r * D64 + d;
  const size_t SL = (size_t)kNSH * D64;
  float s = p[off] + p[SL + off] + p[2 * SL + off] + p[3 * SL + off];
  float v;
  if (EPI == 0) {
    v = s;
  } else if (EPI == 1) {
    v = add[off] + s / fmaxf(sc[r], 1e-12f);
    out[off] = v;
  } else {
    float x = fmaxf((s + add[off]) / sc[r], 0.f);
    float ss = x * x;
#pragma unroll
    for (int o = 32; o; o >>= 1) ss += __shfl_xor(ss, o);
    v = x / fmaxf(sqrtf(ss), 1e-12f);
    if (EPI == 2) out[off] = v;
    else {
      float fv = 0.5f * (raw[off] + v);
      out[off] = fv;
      rm[off] = f2bf(fv);
    }
  }
  if (EPI != 3) {
    tile[d][rl] = f2bf(v);
    __syncthreads();
    if (t < 64) {
      unsigned long long pk;
      unsigned short* pp = reinterpret_cast<unsigned short*>(&pk);
      pp[0] = tile[t][0]; pp[1] = tile[t][1]; pp[2] = tile[t][2]; pp[3] = tile[t][3];
      *reinterpret_cast<unsigned long long*>(&outT[(size_t)t * kNSH + blockIdx.x * 4]) = pk;
    }
  }
}

// ---- merged post-inter l2n -> out block 1, shared rows ----
__global__ void l2n2(const float* __restrict__ es1h, const float* __restrict__ et1h,
                     float* __restrict__ out) {
  const float* in = blockIdx.y ? et1h : es1h;
  size_t row0 = blockIdx.y ? (size_t)kNS : 0;
  int r = blockIdx.x * 4 + (threadIdx.x >> 6);
  int d = threadIdx.x & 63;
  float v = in[(size_t)r * D64 + d];
  float ss = v * v;
#pragma unroll
  for (int o = 32; o; o >>= 1) ss += __shfl_xor(ss, o);
  float n = fmaxf(sqrtf(ss), 1e-12f);
  out[(row0 + (size_t)r) * 256 + 64 + d] = v / n;
}

extern "C" void kernel_launch(void* const* d_in, const int* in_sizes, int n_in,
                              void* d_out, int out_size, void* d_ws, size_t ws_size,
                              hipStream_t stream) {
  const float* src_user = (const float*)d_in[0];
  const float* tgt_user = (const float*)d_in[1];
  const float* src_item = (const float*)d_in[2];
  const float* tgt_item = (const float*)d_in[3];
  const float* mapping  = (const float*)d_in[4];
  const float* s_vals   = (const float*)d_in[5];
  const float* t_vals   = (const float*)d_in[6];
  const int*   s_idx    = (const int*)d_in[7];
  const int*   t_idx    = (const int*)d_in[8];
  float* out = (float*)d_out;

  float* w = (float*)d_ws;
  size_t o = 0;
  float* es1h = w + o; o += (size_t)kNSH * D64;
  float* et1h = w + o; o += (size_t)kNSH * D64;
  float* src2 = w + o; o += (size_t)kNSH * D64;
  float* tgt2 = w + o; o += (size_t)kNSH * D64;
  float* itS  = w + o; o += (size_t)kNSH * D64;
  float* itT  = w + o; o += (size_t)kNSH * D64;
  float* partA = w + o; o += (size_t)4 * kNSH * D64;
  float* partB = w + o; o += (size_t)4 * kNSH * D64;
  float* rs = w + o; o += kNSH;
  float* cs = w + o; o += kNSH;
  float* Ds = w + o; o += kNSH;
  float* Dt = w + o; o += kNSH;
  // bf16 region
  unsigned short* ub = (unsigned short*)(w + o);
  size_t uo = 0;
  unsigned short* Sbf   = ub + uo; uo += (size_t)kNSH * kNSH;
  unsigned short* STbf  = ub + uo; uo += (size_t)kNSH * kNSH;
  unsigned short* tmpbf = ub + uo; uo += (size_t)kNSH * D64;
  unsigned short* tgtbf = ub + uo; uo += (size_t)kNSH * D64;
  unsigned short* tgtT  = ub + uo; uo += (size_t)kNSH * D64;
  unsigned short* src2T = ub + uo; uo += (size_t)kNSH * D64;
  unsigned short* tgt2T = ub + uo; uo += (size_t)kNSH * D64;
  unsigned short* itST  = ub + uo; uo += (size_t)kNSH * D64;
  unsigned short* itTT  = ub + uo; uo += (size_t)kNSH * D64;
  unsigned short* ybAT  = ub + uo; uo += (size_t)kNSH * D64;
  unsigned short* ybBT  = ub + uo; uo += (size_t)kNSH * D64;
  unsigned short* es1b  = ub + uo; uo += (size_t)kNS * D64;
  unsigned short* et1b  = ub + uo; uo += (size_t)kNT * D64;
  unsigned short* es2b  = ub + uo; uo += (size_t)kNS * D64;
  unsigned short* et2b  = ub + uo; uo += (size_t)kNT * D64;
  // int region
  int* iw = (int*)(ub + ((uo + 1) & ~(size_t)1));
  size_t io = 0;
  int* sPtr = iw + io; io += kNS;
  int* sCur = iw + io; io += kNS;
  int* sCnt = iw + io; io += kNS;
  int* tPtr = iw + io; io += kNT;
  int* tCur = iw + io; io += kNT;
  int* tCnt = iw + io; io += kNT;
  int* blk  = iw + io; io += 1024;
  io = (io + 1) & ~(size_t)1;
  int2* sEV = (int2*)(iw + io); io += (size_t)2 * kNNZ;
  int2* tEV = (int2*)(iw + io); io += (size_t)2 * kNNZ;

  const int egrid = (kNNZ + 255) / 256;

  // ---- CSR build (merged) ----
  init_misc<<<(kNS + 255) / 256, 256, 0, stream>>>(sCnt, tCnt, rs, cs);
  histo2<<<dim3(egrid, 2), 256, 0, stream>>>(s_idx, t_idx, sCnt, tCnt);
  scan1m<<<dim3(kNbS, 2), 256, 0, stream>>>(sCnt, sPtr, tCnt, tPtr, blk);
  scan2m<<<1, 128, 0, stream>>>(blk);
  scan3m<<<dim3(kNbS, 2), 256, 0, stream>>>(sPtr, sCur, tPtr, tCur, blk);
  scatter2<<<dim3(egrid, 2), 256, 0, stream>>>(s_idx, s_vals, sCur, sEV,
                                               t_idx, t_vals, tCur, tEV);

  // ---- layer 1 spmm (+ fused raw block-0 store + l2n block-1 for r>=4096) ----
  spmm1<<<(kNS + kNT + 15) / 16, 256, 0, stream>>>(sPtr, sCur, sEV, tPtr, tCur, tEV,
                                                   src_user, src_item, tgt_user, tgt_item,
                                                   es1h, et1h, es1b, et1b, out);

  // ---- inter block ----
  prep_inter<<<dim3(256, 2), 256, 0, stream>>>(es1h, mapping, tmpbf, et1h, tgtbf, tgtT);
  expS_mfma<<<dim3(64, 64), 256, 0, stream>>>(tmpbf, tgtbf, Sbf, STbf, rs, cs);
  rowred2<<<dim3(kNSH, 2), 256, 0, stream>>>(Sbf, cs, Ds, STbf, rs, Dt);
  // src2 = src0 + (S@tgt0)/rs
  sgemm_bf<<<dim3(64, 4, 1), 256, 0, stream>>>(Sbf, tgtT, partA, Sbf, tgtT, partA);
  red_epi<1><<<dim3(1024, 1), 256, 0, stream>>>(partA, es1h, rs, src2, src2T, nullptr, nullptr,
                                                partA, es1h, rs, src2, src2T, nullptr, nullptr);
  // tgt2 = tgt0 + (S^T@src2)/cs
  sgemm_bf<<<dim3(64, 4, 1), 256, 0, stream>>>(STbf, src2T, partA, STbf, src2T, partA);
  red_epi<1><<<dim3(1024, 1), 256, 0, stream>>>(partA, et1h, cs, tgt2, tgt2T, nullptr, nullptr,
                                                partA, et1h, cs, tgt2, tgt2T, nullptr, nullptr);
  // 3 propagation iterations, dual-chain batched
  float* paF = src2; unsigned short* paT = src2T;
  float* pbF = itS;  unsigned short* pbT = itST;
  float* qaF = tgt2; unsigned short* qaT = tgt2T;
  float* qbF = itT;  unsigned short* qbT = itTT;
  for (int itn = 0; itn < 3; ++itn) {
    sgemm_bf<<<dim3(64, 4, 2), 256, 0, stream>>>(STbf, paT, partA, Sbf, qaT, partB);
    red_epi<0><<<dim3(1024, 2), 256, 0, stream>>>(
        partA, nullptr, nullptr, nullptr, ybAT, nullptr, nullptr,
        partB, nullptr, nullptr, nullptr, ybBT, nullptr, nullptr);
    sgemm_bf<<<dim3(64, 4, 2), 256, 0, stream>>>(Sbf, ybAT, partA, STbf, ybBT, partB);
    if (itn < 2) {
      red_epi<2><<<dim3(1024, 2), 256, 0, stream>>>(
          partA, paF, Ds, pbF, pbT, nullptr, nullptr,
          partB, qaF, Dt, qbF, qbT, nullptr, nullptr);
      float* tf = paF; paF = pbF; pbF = tf;
      unsigned short* tt = paT; paT = pbT; pbT = tt;
      tf = qaF; qaF = qbF; qbF = tf;
      tt = qaT; qaT = qbT; qbT = tt;
    } else {
      red_epi<3><<<dim3(1024, 2), 256, 0, stream>>>(
          partA, paF, Ds, es1h, nullptr, es1h, es1b,
          partB, qaF, Dt, et1h, nullptr, et1h, et1b);
    }
  }
  // out block 1, shared rows (post-inter)
  l2n2<<<dim3(kNSH / 4, 2), 256, 0, stream>>>(es1h, et1h, out);

  // ---- layer 2 (bf16 gather; writes es2b/et2b + out block 2) ----
  spmm23<1><<<(kNS + kNT + 31) / 32, 256, 0, stream>>>(sPtr, sCur, sEV, tPtr, tCur, tEV,
                                                       es1b, et1b, es2b, et2b, out, 128);
  // ---- layer 3 (bf16 gather; out block 3 only) ----
  spmm23<0><<<(kNS + kNT + 31) / 32, 256, 0, stream>>>(sPtr, sCur, sEV, tPtr, tCur, tEV,
                                                       es2b, et2b, nullptr, nullptr, out, 192);
}

// Round 6
// 1216.717 us; speedup vs baseline: 11.7010x; 1.0161x over previous
//
#include <hip/hip_runtime.h>
#include <cstdint>
#include <cstddef>

typedef __attribute__((ext_vector_type(8))) short short8;
typedef __attribute__((ext_vector_type(8))) unsigned short ushort8;
typedef __attribute__((ext_vector_type(4))) float f32x4;

#define D64 64
static constexpr int kNU   = 215904;   // N_USERS
static constexpr int kNS   = 275904;   // N_S
static constexpr int kNT   = 265904;   // N_T
static constexpr int kNSH  = 4096;     // N_SHARED
static constexpr int kNNZ  = 2000000;
static constexpr float kTinv = 0.2f;   // 1/T
static constexpr int kScanCh = 2048;
static constexpr int kNbS = (kNS + kScanCh - 1) / kScanCh;  // 135
static constexpr int kNbT = (kNT + kScanCh - 1) / kScanCh;  // 130

__device__ __forceinline__ unsigned short f2bf(float x) {
  unsigned u = __builtin_bit_cast(unsigned, x);
  u += 0x7FFFu + ((u >> 16) & 1u);
  return (unsigned short)(u >> 16);
}
__device__ __forceinline__ float bf2f(unsigned short h) {
  return __builtin_bit_cast(float, (unsigned)h << 16);
}

// ================= init: zero counters + rs/cs =================
__global__ void init_misc(int* __restrict__ sCnt, int* __restrict__ tCnt,
                          float* __restrict__ rs, float* __restrict__ cs) {
  int i = blockIdx.x * 256 + threadIdx.x;
  if (i < kNS) sCnt[i] = 0;
  if (i < kNT) tCnt[i] = 0;
  if (i < kNSH) { rs[i] = 0.f; cs[i] = 0.f; }
}

// ================= CSR build (merged s/t via blockIdx.y) =================
__global__ void histo2(const int* __restrict__ s_idx, const int* __restrict__ t_idx,
                       int* __restrict__ sCnt, int* __restrict__ tCnt) {
  int e = blockIdx.x * 256 + threadIdx.x;
  const int* idx = blockIdx.y ? t_idx : s_idx;
  int* cnt = blockIdx.y ? tCnt : sCnt;
  if (e < kNNZ) atomicAdd(&cnt[idx[e]], 1);
}

__global__ void scan1m(const int* __restrict__ sCnt, int* __restrict__ sPtr,
                       const int* __restrict__ tCnt, int* __restrict__ tPtr,
                       int* __restrict__ blk) {
  int n = blockIdx.y ? kNT : kNS;
  int base = blockIdx.x * kScanCh;
  if (base >= n) return;
  const int* in = blockIdx.y ? tCnt : sCnt;
  int* outp = blockIdx.y ? tPtr : sPtr;
  int* bs = blk + blockIdx.y * 512;
  __shared__ int ts[256];
  int t = threadIdx.x;
  int local[8];
  int s = 0;
#pragma unroll
  for (int i = 0; i < 8; ++i) {
    int g = base + t * 8 + i;
    int v = (g < n) ? in[g] : 0;
    local[i] = s;
    s += v;
  }
  ts[t] = s;
  __syncthreads();
  for (int off = 1; off < 256; off <<= 1) {
    int v = (t >= off) ? ts[t - off] : 0;
    __syncthreads();
    ts[t] += v;
    __syncthreads();
  }
  int excl = (t == 0) ? 0 : ts[t - 1];
  if (t == 255) bs[blockIdx.x] = ts[255];
#pragma unroll
  for (int i = 0; i < 8; ++i) {
    int g = base + t * 8 + i;
    if (g < n) outp[g] = excl + local[i];
  }
}

__global__ void scan2m(int* __restrict__ blk) {
  int t = threadIdx.x;
  if (t == 0) { int s = 0; for (int i = 0; i < kNbS; ++i) { int v = blk[i]; blk[i] = s; s += v; } }
  if (t == 64) { int s = 0; for (int i = 0; i < kNbT; ++i) { int v = blk[512 + i]; blk[512 + i] = s; s += v; } }
}

__global__ void scan3m(int* __restrict__ sPtr, int* __restrict__ sCur,
                       int* __restrict__ tPtr, int* __restrict__ tCur,
                       const int* __restrict__ blk) {
  int n = blockIdx.y ? kNT : kNS;
  int base = blockIdx.x * kScanCh;
  if (base >= n) return;
  int* outp = blockIdx.y ? tPtr : sPtr;
  int* cur = blockIdx.y ? tCur : sCur;
  int add = blk[blockIdx.y * 512 + blockIdx.x];
  int t = threadIdx.x;
#pragma unroll
  for (int i = 0; i < 8; ++i) {
    int g = base + t * 8 + i;
    if (g < n) { int v = outp[g] + add; outp[g] = v; cur[g] = v; }
  }
}

__global__ void scatter2(const int* __restrict__ s_idx, const float* __restrict__ s_vals,
                         int* __restrict__ sCur, int2* __restrict__ sEV,
                         const int* __restrict__ t_idx, const float* __restrict__ t_vals,
                         int* __restrict__ tCur, int2* __restrict__ tEV) {
  int e = blockIdx.x * 256 + threadIdx.x;
  if (e >= kNNZ) return;
  const int* idx = blockIdx.y ? t_idx : s_idx;
  const float* vals = blockIdx.y ? t_vals : s_vals;
  int* cur = blockIdx.y ? tCur : sCur;
  int2* EV = blockIdx.y ? tEV : sEV;
  int r = idx[e];
  int p = atomicAdd(&cur[r], 1);
  EV[p] = make_int2(idx[kNNZ + e], __float_as_int(vals[e]));
}

// ====== cvt_in: raw concat -> out block 0 (exact f32) + unified bf16 copies ======
__global__ void cvt_in(const float* __restrict__ su, const float* __restrict__ si,
                       const float* __restrict__ tu, const float* __restrict__ ti,
                       unsigned short* __restrict__ sub, unsigned short* __restrict__ tub,
                       float* __restrict__ out) {
  int g = blockIdx.x * 16 + (threadIdx.x >> 4);
  bool isS = g < kNS;
  int r = isS ? g : g - kNS;
  if (!isS && r >= kNT) return;
  const float* xu = isS ? su : tu;
  const float* xi = isS ? si : ti;
  int q = (threadIdx.x & 15) << 2;
  const float4 v = *reinterpret_cast<const float4*>(
      ((r < kNU) ? (xu + ((size_t)r << 6)) : (xi + ((size_t)(r - kNU) << 6))) + q);
  *reinterpret_cast<float4*>(out + (size_t)g * 256 + q) = v;
  unsigned long long pk = (unsigned long long)f2bf(v.x) |
                          ((unsigned long long)f2bf(v.y) << 16) |
                          ((unsigned long long)f2bf(v.z) << 32) |
                          ((unsigned long long)f2bf(v.w) << 48);
  *reinterpret_cast<unsigned long long*>((isS ? sub : tub) + ((size_t)r << 6) + q) = pk;
}

// ====== layer-1 SpMM: bf16 gathers (8-lane groups, unroll-4), f32 head + bf16 + l2n out ======
__global__ void spmm1(const int* __restrict__ sPtr, const int* __restrict__ sCur,
                      const int2* __restrict__ sEV,
                      const int* __restrict__ tPtr, const int* __restrict__ tCur,
                      const int2* __restrict__ tEV,
                      const unsigned short* __restrict__ sub, const unsigned short* __restrict__ tub,
                      float* __restrict__ es1h, float* __restrict__ et1h,
                      unsigned short* __restrict__ es1b, unsigned short* __restrict__ et1b,
                      float* __restrict__ out) {
  int g = blockIdx.x * 32 + (threadIdx.x >> 3);
  bool isS = g < kNS;
  int r = isS ? g : g - kNS;
  if (!isS && r >= kNT) return;
  const int* Pp = isS ? sPtr : tPtr;
  const int* Pc = isS ? sCur : tCur;
  const int2* EV = isS ? sEV : tEV;
  const unsigned short* xb = isS ? sub : tub;
  int q = (threadIdx.x & 7) << 3;
  int beg = Pp[r], end = Pc[r];
  float acc[8] = {0.f, 0.f, 0.f, 0.f, 0.f, 0.f, 0.f, 0.f};
  int i = beg;
  for (; i + 4 <= end; i += 4) {
    int2 e0 = EV[i], e1 = EV[i + 1], e2 = EV[i + 2], e3 = EV[i + 3];
    ushort8 x0 = *reinterpret_cast<const ushort8*>(xb + ((size_t)e0.x << 6) + q);
    ushort8 x1 = *reinterpret_cast<const ushort8*>(xb + ((size_t)e1.x << 6) + q);
    ushort8 x2 = *reinterpret_cast<const ushort8*>(xb + ((size_t)e2.x << 6) + q);
    ushort8 x3 = *reinterpret_cast<const ushort8*>(xb + ((size_t)e3.x << 6) + q);
    float v0 = __int_as_float(e0.y), v1 = __int_as_float(e1.y);
    float v2 = __int_as_float(e2.y), v3 = __int_as_float(e3.y);
#pragma unroll
    for (int j = 0; j < 8; ++j) {
      float a = fmaf(v0, bf2f((unsigned short)x0[j]), fmaf(v1, bf2f((unsigned short)x1[j]), acc[j]));
      acc[j] = fmaf(v2, bf2f((unsigned short)x2[j]), fmaf(v3, bf2f((unsigned short)x3[j]), a));
    }
  }
  for (; i + 2 <= end; i += 2) {
    int2 e0 = EV[i], e1 = EV[i + 1];
    ushort8 x0 = *reinterpret_cast<const ushort8*>(xb + ((size_t)e0.x << 6) + q);
    ushort8 x1 = *reinterpret_cast<const ushort8*>(xb + ((size_t)e1.x << 6) + q);
    float v0 = __int_as_float(e0.y), v1 = __int_as_float(e1.y);
#pragma unroll
    for (int j = 0; j < 8; ++j)
      acc[j] = fmaf(v0, bf2f((unsigned short)x0[j]), fmaf(v1, bf2f((unsigned short)x1[j]), acc[j]));
  }
  if (i < end) {
    int2 e0 = EV[i];
    ushort8 x0 = *reinterpret_cast<const ushort8*>(xb + ((size_t)e0.x << 6) + q);
    float v0 = __int_as_float(e0.y);
#pragma unroll
    for (int j = 0; j < 8; ++j) acc[j] = fmaf(v0, bf2f((unsigned short)x0[j]), acc[j]);
  }
  // f32 head (rows < 4096 feed the inter block)
  if (r < kNSH) {
    float* eh = isS ? es1h : et1h;
    *reinterpret_cast<float4*>(eh + ((size_t)r << 6) + q) =
        make_float4(acc[0], acc[1], acc[2], acc[3]);
    *reinterpret_cast<float4*>(eh + ((size_t)r << 6) + q + 4) =
        make_float4(acc[4], acc[5], acc[6], acc[7]);
  }
  // bf16 full copy (layer-2 gather source)
  {
    unsigned short* eb = isS ? es1b : et1b;
    ushort8 o;
#pragma unroll
    for (int j = 0; j < 8; ++j) o[j] = f2bf(acc[j]);
    *reinterpret_cast<ushort8*>(eb + ((size_t)r << 6) + q) = o;
  }
  // l2n + out block 1 for non-shared rows
  float ss = 0.f;
#pragma unroll
  for (int j = 0; j < 8; ++j) ss += acc[j] * acc[j];
  ss += __shfl_xor(ss, 1); ss += __shfl_xor(ss, 2); ss += __shfl_xor(ss, 4);
  float inv = 1.f / fmaxf(sqrtf(ss), 1e-12f);
  if (r >= kNSH) {
    float* op = out + (size_t)g * 256 + 64 + q;
    *reinterpret_cast<float4*>(op) = make_float4(acc[0] * inv, acc[1] * inv, acc[2] * inv, acc[3] * inv);
    *reinterpret_cast<float4*>(op + 4) = make_float4(acc[4] * inv, acc[5] * inv, acc[6] * inv, acc[7] * inv);
  }
}

// ====== layers 2/3 SpMM: bf16 gathers (8-lane groups, unroll-4), fused l2n out store ======
template <int WRITE_Y>
__global__ void spmm23(const int* __restrict__ sPtr, const int* __restrict__ sCur,
                       const int2* __restrict__ sEV,
                       const int* __restrict__ tPtr, const int* __restrict__ tCur,
                       const int2* __restrict__ tEV,
                       const unsigned short* __restrict__ xs, const unsigned short* __restrict__ xt,
                       unsigned short* __restrict__ ys, unsigned short* __restrict__ yt,
                       float* __restrict__ out, int coff) {
  int g = blockIdx.x * 32 + (threadIdx.x >> 3);
  bool isS = g < kNS;
  int r = isS ? g : g - kNS;
  if (!isS && r >= kNT) return;
  const int* Pp = isS ? sPtr : tPtr;
  const int* Pc = isS ? sCur : tCur;
  const int2* EV = isS ? sEV : tEV;
  const unsigned short* xb = isS ? xs : xt;
  int q = (threadIdx.x & 7) << 3;
  int beg = Pp[r], end = Pc[r];
  float acc[8] = {0.f, 0.f, 0.f, 0.f, 0.f, 0.f, 0.f, 0.f};
  int i = beg;
  for (; i + 4 <= end; i += 4) {
    int2 e0 = EV[i], e1 = EV[i + 1], e2 = EV[i + 2], e3 = EV[i + 3];
    ushort8 x0 = *reinterpret_cast<const ushort8*>(xb + ((size_t)e0.x << 6) + q);
    ushort8 x1 = *reinterpret_cast<const ushort8*>(xb + ((size_t)e1.x << 6) + q);
    ushort8 x2 = *reinterpret_cast<const ushort8*>(xb + ((size_t)e2.x << 6) + q);
    ushort8 x3 = *reinterpret_cast<const ushort8*>(xb + ((size_t)e3.x << 6) + q);
    float v0 = __int_as_float(e0.y), v1 = __int_as_float(e1.y);
    float v2 = __int_as_float(e2.y), v3 = __int_as_float(e3.y);
#pragma unroll
    for (int j = 0; j < 8; ++j) {
      float a = fmaf(v0, bf2f((unsigned short)x0[j]), fmaf(v1, bf2f((unsigned short)x1[j]), acc[j]));
      acc[j] = fmaf(v2, bf2f((unsigned short)x2[j]), fmaf(v3, bf2f((unsigned short)x3[j]), a));
    }
  }
  for (; i + 2 <= end; i += 2) {
    int2 e0 = EV[i], e1 = EV[i + 1];
    ushort8 x0 = *reinterpret_cast<const ushort8*>(xb + ((size_t)e0.x << 6) + q);
    ushort8 x1 = *reinterpret_cast<const ushort8*>(xb + ((size_t)e1.x << 6) + q);
    float v0 = __int_as_float(e0.y), v1 = __int_as_float(e1.y);
#pragma unroll
    for (int j = 0; j < 8; ++j)
      acc[j] = fmaf(v0, bf2f((unsigned short)x0[j]), fmaf(v1, bf2f((unsigned short)x1[j]), acc[j]));
  }
  if (i < end) {
    int2 e0 = EV[i];
    ushort8 x0 = *reinterpret_cast<const ushort8*>(xb + ((size_t)e0.x << 6) + q);
    float v0 = __int_as_float(e0.y);
#pragma unroll
    for (int j = 0; j < 8; ++j) acc[j] = fmaf(v0, bf2f((unsigned short)x0[j]), acc[j]);
  }
  if (WRITE_Y) {
    unsigned short* yb = isS ? ys : yt;
    ushort8 o;
#pragma unroll
    for (int j = 0; j < 8; ++j) o[j] = f2bf(acc[j]);
    *reinterpret_cast<ushort8*>(yb + ((size_t)r << 6) + q) = o;
  }
  float ss = 0.f;
#pragma unroll
  for (int j = 0; j < 8; ++j) ss += acc[j] * acc[j];
  ss += __shfl_xor(ss, 1); ss += __shfl_xor(ss, 2); ss += __shfl_xor(ss, 4);
  float inv = 1.f / fmaxf(sqrtf(ss), 1e-12f);
  float* op = out + (size_t)g * 256 + coff + q;
  *reinterpret_cast<float4*>(op) = make_float4(acc[0] * inv, acc[1] * inv, acc[2] * inv, acc[3] * inv);
  *reinterpret_cast<float4*>(op + 4) = make_float4(acc[4] * inv, acc[5] * inv, acc[6] * inv, acc[7] * inv);
}

// ---------------- merged: tmp = src0@mapping (bf16 out) | cvt tgt0 -> bf16 row+col ----------------
__global__ void prep_inter(const float* __restrict__ A, const float* __restrict__ M,
                           unsigned short* __restrict__ tmpbf,
                           const float* __restrict__ Tg, unsigned short* __restrict__ rowmaj,
                           unsigned short* __restrict__ colmaj) {
  int t = threadIdx.x;
  if (blockIdx.y == 0) {
    __shared__ float Xs[64][65];
    __shared__ float As[16][65];
    int r0 = blockIdx.x * 16;
    int d = t & 63, rg = t >> 6;
    float acc[4] = {0.f, 0.f, 0.f, 0.f};
    for (int l = t; l < 1024; l += 256) {
      int r = l >> 4, c = (l & 15) << 2;
      float4 xv = *reinterpret_cast<const float4*>(M + (size_t)r * D64 + c);
      Xs[r][c] = xv.x; Xs[r][c + 1] = xv.y; Xs[r][c + 2] = xv.z; Xs[r][c + 3] = xv.w;
    }
    {
      int r = t >> 4, c = (t & 15) << 2;
      float4 av = *reinterpret_cast<const float4*>(A + (size_t)(r0 + r) * D64 + c);
      As[r][c] = av.x; As[r][c + 1] = av.y; As[r][c + 2] = av.z; As[r][c + 3] = av.w;
    }
    __syncthreads();
    for (int k = 0; k < 64; ++k) {
      float xv = Xs[k][d];
#pragma unroll
      for (int rr = 0; rr < 4; ++rr) acc[rr] += As[rg * 4 + rr][k] * xv;
    }
#pragma unroll
    for (int rr = 0; rr < 4; ++rr)
      tmpbf[(size_t)(r0 + rg * 4 + rr) * D64 + d] = f2bf(acc[rr]);
  } else {
    if (blockIdx.x >= 64) return;
    __shared__ unsigned short tile[64][72];
    int r0 = blockIdx.x * 64;
    int r = t >> 2, cq = (t & 3) << 4;
    unsigned short buf[16] __attribute__((aligned(16)));
#pragma unroll
    for (int j = 0; j < 16; j += 4) {
      float4 v = *reinterpret_cast<const float4*>(Tg + (size_t)(r0 + r) * D64 + cq + j);
      buf[j] = f2bf(v.x); buf[j + 1] = f2bf(v.y); buf[j + 2] = f2bf(v.z); buf[j + 3] = f2bf(v.w);
    }
#pragma unroll
    for (int j = 0; j < 16; ++j) tile[r][cq + j] = buf[j];
    *reinterpret_cast<ushort8*>(&rowmaj[(size_t)(r0 + r) * D64 + cq]) =
        *reinterpret_cast<ushort8*>(&buf[0]);
    *reinterpret_cast<ushort8*>(&rowmaj[(size_t)(r0 + r) * D64 + cq + 8]) =
        *reinterpret_cast<ushort8*>(&buf[8]);
    __syncthreads();
    int c = t >> 2, rq = (t & 3) << 4;
#pragma unroll
    for (int j = 0; j < 16; ++j) buf[j] = tile[rq + j][c];
    *reinterpret_cast<ushort8*>(&colmaj[(size_t)c * kNSH + r0 + rq]) =
        *reinterpret_cast<ushort8*>(&buf[0]);
    *reinterpret_cast<ushort8*>(&colmaj[(size_t)c * kNSH + r0 + rq + 8]) =
        *reinterpret_cast<ushort8*>(&buf[8]);
  }
}

// ======== MFMA: S=exp((tmp@tgt0^T)/T) -> Sbf, STbf (bf16), rs/cs (f32) ========
__global__ void expS_mfma(const unsigned short* __restrict__ Abf,
                          const unsigned short* __restrict__ Bbf,
                          unsigned short* __restrict__ Sbf, unsigned short* __restrict__ STbf,
                          float* __restrict__ rs, float* __restrict__ cs) {
  __shared__ unsigned short Cs[64][72];
  __shared__ float csred[4][64];
  int j0 = blockIdx.x * 64, i0 = blockIdx.y * 64;
  int t = threadIdx.x;
  int w = t >> 6, l = t & 63;
  int lr = l & 15, lk = (l >> 4) << 3;
  f32x4 acc[4] = {};
  const unsigned short* Ap = Abf + (size_t)(i0 + w * 16 + lr) * D64 + lk;
#pragma unroll
  for (int ks = 0; ks < 2; ++ks) {
    short8 a = *reinterpret_cast<const short8*>(Ap + ks * 32);
#pragma unroll
    for (int nt = 0; nt < 4; ++nt) {
      short8 b = *reinterpret_cast<const short8*>(
          Bbf + (size_t)(j0 + nt * 16 + lr) * D64 + ks * 32 + lk);
      acc[nt] = __builtin_amdgcn_mfma_f32_16x16x32_bf16(a, b, acc[nt], 0, 0, 0);
    }
  }
  float rowpart[4] = {0.f, 0.f, 0.f, 0.f};
#pragma unroll
  for (int nt = 0; nt < 4; ++nt) {
    float colpart = 0.f;
#pragma unroll
    for (int rg = 0; rg < 4; ++rg) {
      float e = __expf(acc[nt][rg] * kTinv);
      acc[nt][rg] = e;
      rowpart[rg] += e;
      colpart += e;
      Cs[w * 16 + (l >> 4) * 4 + rg][nt * 16 + lr] = f2bf(e);
    }
    float v = colpart;
    v += __shfl_xor(v, 16); v += __shfl_xor(v, 32);
    if (l < 16) csred[w][nt * 16 + l] = v;
  }
#pragma unroll
  for (int rg = 0; rg < 4; ++rg) {
    float v = rowpart[rg];
    v += __shfl_xor(v, 1); v += __shfl_xor(v, 2);
    v += __shfl_xor(v, 4); v += __shfl_xor(v, 8);
    if (lr == 0) atomicAdd(&rs[i0 + w * 16 + (l >> 4) * 4 + rg], v);
  }
  __syncthreads();
  if (t < 64) atomicAdd(&cs[j0 + t], csred[0][t] + csred[1][t] + csred[2][t] + csred[3][t]);
  {
    int r = t >> 2, cq = (t & 3) << 4;
    ushort8 v0 = *reinterpret_cast<const ushort8*>(&Cs[r][cq]);
    ushort8 v1 = *reinterpret_cast<const ushort8*>(&Cs[r][cq + 8]);
    *reinterpret_cast<ushort8*>(&Sbf[(size_t)(i0 + r) * kNSH + j0 + cq]) = v0;
    *reinterpret_cast<ushort8*>(&Sbf[(size_t)(i0 + r) * kNSH + j0 + cq + 8]) = v1;
    int c = t >> 2, rq = (t & 3) << 4;
    unsigned short buf[16] __attribute__((aligned(16)));
#pragma unroll
    for (int j = 0; j < 16; ++j) buf[j] = Cs[rq + j][c];
    *reinterpret_cast<ushort8*>(&STbf[(size_t)(j0 + c) * kNSH + i0 + rq]) =
        *reinterpret_cast<ushort8*>(&buf[0]);
    *reinterpret_cast<ushort8*>(&STbf[(size_t)(j0 + c) * kNSH + i0 + rq + 8]) =
        *reinterpret_cast<ushort8*>(&buf[8]);
  }
}

// ---- merged Ds/Dt: y=0 -> Ds[i]=sum Sbf[i][j]*cs[j]+1; y=1 -> Dt[i]=sum STbf[i][j]*rs[j]+1 ----
__global__ void rowred2(const unsigned short* __restrict__ Sbf, const float* __restrict__ cs,
                        float* __restrict__ Ds,
                        const unsigned short* __restrict__ STbf, const float* __restrict__ rs,
                        float* __restrict__ Dt) {
  const unsigned short* Sb = blockIdx.y ? STbf : Sbf;
  const float* w = blockIdx.y ? rs : cs;
  float* outp = blockIdx.y ? Dt : Ds;
  int i = blockIdx.x;
  const unsigned short* row = Sb + (size_t)i * kNSH;
  int t = threadIdx.x;
  float acc = 0.f;
  for (int j0 = t * 8; j0 < kNSH; j0 += 2048) {
    short8 v = *reinterpret_cast<const short8*>(row + j0);
#pragma unroll
    for (int j = 0; j < 8; ++j) acc += bf2f((unsigned short)v[j]) * w[j0 + j];
  }
#pragma unroll
  for (int o = 32; o; o >>= 1) acc += __shfl_xor(acc, o);
  __shared__ float red[4];
  if ((t & 63) == 0) red[t >> 6] = acc;
  __syncthreads();
  if (t == 0) outp[i] = red[0] + red[1] + red[2] + red[3] + 1.f;
}

// ======== dual-chain MFMA skinny GEMM ========
__global__ void sgemm_bf(const unsigned short* __restrict__ aA, const unsigned short* __restrict__ xA,
                         float* __restrict__ pA,
                         const unsigned short* __restrict__ aB, const unsigned short* __restrict__ xB,
                         float* __restrict__ pB) {
  const unsigned short* A = (blockIdx.z == 0) ? aA : aB;
  const unsigned short* X = (blockIdx.z == 0) ? xA : xB;
  float* P = (blockIdx.z == 0) ? pA : pB;
  int t = threadIdx.x;
  int w = t >> 6, l = t & 63;
  int lr = l & 15, lk = (l >> 4) << 3;
  int m0 = blockIdx.x * 64 + w * 16;
  int k0 = blockIdx.y * 1024;
  f32x4 acc[4] = {};
  const unsigned short* Ap = A + (size_t)(m0 + lr) * kNSH + k0 + lk;
  const unsigned short* Xp = X + (size_t)lr * kNSH + k0 + lk;
  for (int ks = 0; ks < 32; ++ks) {
    short8 a = *reinterpret_cast<const short8*>(Ap + ks * 32);
#pragma unroll
    for (int nt = 0; nt < 4; ++nt) {
      short8 b = *reinterpret_cast<const short8*>(Xp + (size_t)nt * 16 * kNSH + ks * 32);
      acc[nt] = __builtin_amdgcn_mfma_f32_16x16x32_bf16(a, b, acc[nt], 0, 0, 0);
    }
  }
  float* Pp = P + ((size_t)blockIdx.y * kNSH + m0) * D64;
#pragma unroll
  for (int nt = 0; nt < 4; ++nt)
#pragma unroll
    for (int rg = 0; rg < 4; ++rg)
      Pp[(size_t)((l >> 4) * 4 + rg) * D64 + nt * 16 + lr] = acc[nt][rg];
}

// ======== split-K reduce + epilogue (dual-chain via blockIdx.y) ========
// EPI 0: outT = bf16(sum)
// EPI 1: out = ADD + sum/max(SC,eps); outT = bf16
// EPI 2: out = l2n(relu((sum+ADD)/SC)); outT = bf16
// EPI 3: fv = 0.5*(RAW + l2n(relu((sum+ADD)/SC))); RM = bf16(fv);
//        gout[grow0 + r][64..127] = l2n(fv)   (fused final out block-1 store)
template <int EPI>
__global__ void red_epi(const float* __restrict__ pA, const float* __restrict__ addA,
                        const float* __restrict__ scA, float* __restrict__ outA,
                        unsigned short* __restrict__ outTA, const float* __restrict__ rawA,
                        unsigned short* __restrict__ rmA,
                        const float* __restrict__ pB, const float* __restrict__ addB,
                        const float* __restrict__ scB, float* __restrict__ outB,
                        unsigned short* __restrict__ outTB, const float* __restrict__ rawB,
                        unsigned short* __restrict__ rmB,
                        float* __restrict__ gout) {
  const float* p = (blockIdx.y == 0) ? pA : pB;
  const float* add = (blockIdx.y == 0) ? addA : addB;
  const float* sc = (blockIdx.y == 0) ? scA : scB;
  float* out = (blockIdx.y == 0) ? outA : outB;
  unsigned short* outT = (blockIdx.y == 0) ? outTA : outTB;
  const float* raw = (blockIdx.y == 0) ? rawA : rawB;
  unsigned short* rm = (blockIdx.y == 0) ? rmA : rmB;
  __shared__ unsigned short tile[64][4];
  int t = threadIdx.x;
  int d = t & 63, rl = t >> 6;
  int r = blockIdx.x * 4 + rl;
  size_t off = (size_t)r * D64 + d;
  const size_t SL = (size_t)kNSH * D64;
  float s = p[off] + p[SL + off] + p[2 * SL + off] + p[3 * SL + off];
  float v;
  if (EPI == 0) {
    v = s;
  } else if (EPI == 1) {
    v = add[off] + s / fmaxf(sc[r], 1e-12f);
    out[off] = v;
  } else {
    float x = fmaxf((s + add[off]) / sc[r], 0.f);
    float ss = x * x;
#pragma unroll
    for (int o = 32; o; o >>= 1) ss += __shfl_xor(ss, o);
    v = x / fmaxf(sqrtf(ss), 1e-12f);
    if (EPI == 2) out[off] = v;
    else {
      float fv = 0.5f * (raw[off] + v);
      rm[off] = f2bf(fv);
      float s2 = fv * fv;
#pragma unroll
      for (int o = 32; o; o >>= 1) s2 += __shfl_xor(s2, o);
      float nv = fv / fmaxf(sqrtf(s2), 1e-12f);
      size_t grow0 = (blockIdx.y == 0) ? 0 : (size_t)kNS;
      gout[(grow0 + (size_t)r) * 256 + 64 + d] = nv;
    }
  }
  if (EPI != 3) {
    tile[d][rl] = f2bf(v);
    __syncthreads();
    if (t < 64) {
      unsigned long long pk;
      unsigned short* pp = reinterpret_cast<unsigned short*>(&pk);
      pp[0] = tile[t][0]; pp[1] = tile[t][1]; pp[2] = tile[t][2]; pp[3] = tile[t][3];
      *reinterpret_cast<unsigned long long*>(&outT[(size_t)t * kNSH + blockIdx.x * 4]) = pk;
    }
  }
}

extern "C" void kernel_launch(void* const* d_in, const int* in_sizes, int n_in,
                              void* d_out, int out_size, void* d_ws, size_t ws_size,
                              hipStream_t stream) {
  const float* src_user = (const float*)d_in[0];
  const float* tgt_user = (const float*)d_in[1];
  const float* src_item = (const float*)d_in[2];
  const float* tgt_item = (const float*)d_in[3];
  const float* mapping  = (const float*)d_in[4];
  const float* s_vals   = (const float*)d_in[5];
  const float* t_vals   = (const float*)d_in[6];
  const int*   s_idx    = (const int*)d_in[7];
  const int*   t_idx    = (const int*)d_in[8];
  float* out = (float*)d_out;

  float* w = (float*)d_ws;
  size_t o = 0;
  float* es1h = w + o; o += (size_t)kNSH * D64;
  float* et1h = w + o; o += (size_t)kNSH * D64;
  float* src2 = w + o; o += (size_t)kNSH * D64;
  float* tgt2 = w + o; o += (size_t)kNSH * D64;
  float* itS  = w + o; o += (size_t)kNSH * D64;
  float* itT  = w + o; o += (size_t)kNSH * D64;
  float* partA = w + o; o += (size_t)4 * kNSH * D64;
  float* partB = w + o; o += (size_t)4 * kNSH * D64;
  float* rs = w + o; o += kNSH;
  float* cs = w + o; o += kNSH;
  float* Ds = w + o; o += kNSH;
  float* Dt = w + o; o += kNSH;
  // bf16 region
  unsigned short* ub = (unsigned short*)(w + o);
  size_t uo = 0;
  unsigned short* Sbf   = ub + uo; uo += (size_t)kNSH * kNSH;
  unsigned short* STbf  = ub + uo; uo += (size_t)kNSH * kNSH;
  unsigned short* tmpbf = ub + uo; uo += (size_t)kNSH * D64;
  unsigned short* tgtbf = ub + uo; uo += (size_t)kNSH * D64;
  unsigned short* tgtT  = ub + uo; uo += (size_t)kNSH * D64;
  unsigned short* src2T = ub + uo; uo += (size_t)kNSH * D64;
  unsigned short* tgt2T = ub + uo; uo += (size_t)kNSH * D64;
  unsigned short* itST  = ub + uo; uo += (size_t)kNSH * D64;
  unsigned short* itTT  = ub + uo; uo += (size_t)kNSH * D64;
  unsigned short* ybAT  = ub + uo; uo += (size_t)kNSH * D64;
  unsigned short* ybBT  = ub + uo; uo += (size_t)kNSH * D64;
  unsigned short* sub   = ub + uo; uo += (size_t)kNS * D64;   // bf16 layer-1 inputs
  unsigned short* tub   = ub + uo; uo += (size_t)kNT * D64;
  unsigned short* es1b  = ub + uo; uo += (size_t)kNS * D64;
  unsigned short* et1b  = ub + uo; uo += (size_t)kNT * D64;
  unsigned short* es2b  = ub + uo; uo += (size_t)kNS * D64;
  unsigned short* et2b  = ub + uo; uo += (size_t)kNT * D64;
  // int region
  int* iw = (int*)(ub + ((uo + 1) & ~(size_t)1));
  size_t io = 0;
  int* sPtr = iw + io; io += kNS;
  int* sCur = iw + io; io += kNS;
  int* sCnt = iw + io; io += kNS;
  int* tPtr = iw + io; io += kNT;
  int* tCur = iw + io; io += kNT;
  int* tCnt = iw + io; io += kNT;
  int* blk  = iw + io; io += 1024;
  io = (io + 1) & ~(size_t)1;
  int2* sEV = (int2*)(iw + io); io += (size_t)2 * kNNZ;
  int2* tEV = (int2*)(iw + io); io += (size_t)2 * kNNZ;

  const int egrid = (kNNZ + 255) / 256;

  // ---- CSR build (merged) ----
  init_misc<<<(kNS + 255) / 256, 256, 0, stream>>>(sCnt, tCnt, rs, cs);
  histo2<<<dim3(egrid, 2), 256, 0, stream>>>(s_idx, t_idx, sCnt, tCnt);
  scan1m<<<dim3(kNbS, 2), 256, 0, stream>>>(sCnt, sPtr, tCnt, tPtr, blk);
  scan2m<<<1, 128, 0, stream>>>(blk);
  scan3m<<<dim3(kNbS, 2), 256, 0, stream>>>(sPtr, sCur, tPtr, tCur, blk);
  scatter2<<<dim3(egrid, 2), 256, 0, stream>>>(s_idx, s_vals, sCur, sEV,
                                               t_idx, t_vals, tCur, tEV);

  // ---- raw block-0 store + bf16 input copies ----
  cvt_in<<<(kNS + kNT + 15) / 16, 256, 0, stream>>>(src_user, src_item, tgt_user, tgt_item,
                                                    sub, tub, out);

  // ---- layer 1 spmm (bf16 gathers; f32 head + bf16 copy + l2n block-1 for r>=4096) ----
  spmm1<<<(kNS + kNT + 31) / 32, 256, 0, stream>>>(sPtr, sCur, sEV, tPtr, tCur, tEV,
                                                   sub, tub, es1h, et1h, es1b, et1b, out);

  // ---- inter block ----
  prep_inter<<<dim3(256, 2), 256, 0, stream>>>(es1h, mapping, tmpbf, et1h, tgtbf, tgtT);
  expS_mfma<<<dim3(64, 64), 256, 0, stream>>>(tmpbf, tgtbf, Sbf, STbf, rs, cs);
  rowred2<<<dim3(kNSH, 2), 256, 0, stream>>>(Sbf, cs, Ds, STbf, rs, Dt);
  // src2 = src0 + (S@tgt0)/rs
  sgemm_bf<<<dim3(64, 4, 1), 256, 0, stream>>>(Sbf, tgtT, partA, Sbf, tgtT, partA);
  red_epi<1><<<dim3(1024, 1), 256, 0, stream>>>(partA, es1h, rs, src2, src2T, nullptr, nullptr,
                                                partA, es1h, rs, src2, src2T, nullptr, nullptr, out);
  // tgt2 = tgt0 + (S^T@src2)/cs
  sgemm_bf<<<dim3(64, 4, 1), 256, 0, stream>>>(STbf, src2T, partA, STbf, src2T, partA);
  red_epi<1><<<dim3(1024, 1), 256, 0, stream>>>(partA, et1h, cs, tgt2, tgt2T, nullptr, nullptr,
                                                partA, et1h, cs, tgt2, tgt2T, nullptr, nullptr, out);
  // 3 propagation iterations, dual-chain batched
  float* paF = src2; unsigned short* paT = src2T;
  float* pbF = itS;  unsigned short* pbT = itST;
  float* qaF = tgt2; unsigned short* qaT = tgt2T;
  float* qbF = itT;  unsigned short* qbT = itTT;
  for (int itn = 0; itn < 3; ++itn) {
    sgemm_bf<<<dim3(64, 4, 2), 256, 0, stream>>>(STbf, paT, partA, Sbf, qaT, partB);
    red_epi<0><<<dim3(1024, 2), 256, 0, stream>>>(
        partA, nullptr, nullptr, nullptr, ybAT, nullptr, nullptr,
        partB, nullptr, nullptr, nullptr, ybBT, nullptr, nullptr, out);
    sgemm_bf<<<dim3(64, 4, 2), 256, 0, stream>>>(Sbf, ybAT, partA, STbf, ybBT, partB);
    if (itn < 2) {
      red_epi<2><<<dim3(1024, 2), 256, 0, stream>>>(
          partA, paF, Ds, pbF, pbT, nullptr, nullptr,
          partB, qaF, Dt, qbF, qbT, nullptr, nullptr, out);
      float* tf = paF; paF = pbF; pbF = tf;
      unsigned short* tt = paT; paT = pbT; pbT = tt;
      tf = qaF; qaF = qbF; qbF = tf;
      tt = qaT; qaT = qbT; qbT = tt;
    } else {
      // final: bf16 head rewrite + fused l2n -> out block-1 shared rows
      red_epi<3><<<dim3(1024, 2), 256, 0, stream>>>(
          partA, paF, Ds, nullptr, nullptr, es1h, es1b,
          partB, qaF, Dt, nullptr, nullptr, et1h, et1b, out);
    }
  }

  // ---- layer 2 (bf16 gather; writes es2b/et2b + out block 2) ----
  spmm23<1><<<(kNS + kNT + 31) / 32, 256, 0, stream>>>(sPtr, sCur, sEV, tPtr, tCur, tEV,
                                                       es1b, et1b, es2b, et2b, out, 128);
  // ---- layer 3 (bf16 gather; out block 3 only) ----
  spmm23<0><<<(kNS + kNT + 31) / 32, 256, 0, stream>>>(sPtr, sCur, sEV, tPtr, tCur, tEV,
                                                       es2b, et2b, nullptr, nullptr, out, 192);
}